// Round 1
// baseline (340.142 us; speedup 1.0000x reference)
//
#include <hip/hip_runtime.h>
#include <hip/hip_bf16.h>
#include <math.h>

// Problem constants (match reference)
#define TT 7
#define BB 512
#define PP 200
#define QQ 64
#define WWH 64
#define WF 256
#define CC 10
#define NN (BB * PP)          // 102400
#define TQ (TT * QQ)          // 448

// ---------------------------------------------------------------------------
// Kernel 1: per-point weight MLP  w = sigmoid(w3 . relu(W2 relu(W1 x + b1) + b2) + b3)
// One thread per (t,n) point. All weight reads are wave-uniform -> scalar loads.
// ---------------------------------------------------------------------------
__global__ __launch_bounds__(256) void point_weight_kernel(
    const float* __restrict__ diagms,   // [T*N, 2]
    const float* __restrict__ w1,       // [2,64]
    const float* __restrict__ b1,       // [64]
    const float* __restrict__ w2,       // [64,64]
    const float* __restrict__ b2,       // [64]
    const float* __restrict__ w3,       // [64]
    const float* __restrict__ b3,       // [1]
    float* __restrict__ w_out,          // [T*N]
    int total)
{
    int idx = blockIdx.x * blockDim.x + threadIdx.x;
    if (idx >= total) return;

    const float2 d = reinterpret_cast<const float2*>(diagms)[idx];
    const float x = d.x, y = d.y;

    float h1[WWH];
#pragma unroll
    for (int j = 0; j < WWH; ++j) {
        h1[j] = fmaxf(fmaf(x, w1[j], fmaf(y, w1[WWH + j], b1[j])), 0.0f);
    }

    float wacc = b3[0];
#pragma unroll 4
    for (int k = 0; k < WWH; ++k) {
        float a0 = b2[k], a1 = 0.0f, a2 = 0.0f, a3 = 0.0f;
#pragma unroll
        for (int j = 0; j < WWH; j += 4) {
            a0 = fmaf(h1[j + 0], w2[(j + 0) * WWH + k], a0);
            a1 = fmaf(h1[j + 1], w2[(j + 1) * WWH + k], a1);
            a2 = fmaf(h1[j + 2], w2[(j + 2) * WWH + k], a2);
            a3 = fmaf(h1[j + 3], w2[(j + 3) * WWH + k], a3);
        }
        float hk = fmaxf((a0 + a1) + (a2 + a3), 0.0f);
        wacc = fmaf(hk, w3[k], wacc);
    }
    // sigmoid
    w_out[idx] = 1.0f / (1.0f + expf(-wacc));
}

// ---------------------------------------------------------------------------
// Kernel 2: gaussian rep * weight, mean-pool per segment.
// One block per (t,b) segment of P=200 points. 256 thr = 64 q  x  4 groups.
// Writes pooled directly in topo layout [B, T*Q].
// ---------------------------------------------------------------------------
__global__ __launch_bounds__(256) void rep_pool_kernel(
    const float* __restrict__ diagms,   // [T*N, 2]
    const float* __restrict__ theta,    // [Q,2]
    const float* __restrict__ w_in,     // [T*N]
    float* __restrict__ pooled)         // [B, T*Q]
{
    const int bid = blockIdx.x;         // t*B + b
    const int t = bid >> 9;             // / 512
    const int b = bid & (BB - 1);       // % 512
    const int tid = threadIdx.x;

    __shared__ float px[PP];
    __shared__ float py[PP];
    __shared__ float wv[PP];

    if (tid < PP) {
        const int n = t * NN + b * PP + tid;
        const float2 d = reinterpret_cast<const float2*>(diagms)[n];
        px[tid] = d.x;
        py[tid] = d.y;
        wv[tid] = w_in[n];
    }
    __syncthreads();

    const int q = tid & (QQ - 1);
    const int g = tid >> 6;             // 0..3, uniform per wave
    const float tx = theta[2 * q];
    const float ty = theta[2 * q + 1];

    float acc = 0.0f;
    const int p0 = g * (PP / 4);
#pragma unroll 5
    for (int p = p0; p < p0 + PP / 4; ++p) {
        const float dx = px[p] - tx;
        const float dy = py[p] - ty;
        acc = fmaf(wv[p], expf(-50.0f * fmaf(dx, dx, dy * dy)), acc);
    }

    __shared__ float part[4][QQ];
    part[g][q] = acc;
    __syncthreads();

    if (tid < QQ) {
        const float s = (part[0][tid] + part[1][tid]) + (part[2][tid] + part[3][tid]);
        pooled[b * TQ + t * QQ + tid] = s * (1.0f / (float)PP);
    }
}

// ---------------------------------------------------------------------------
// Kernel 3: rho MLP.  out = relu(relu(topo@r1+rb1)@r2+rb2)@r3+rb3
// 4 batch rows per block, 256 threads (thread = output feature k).
// topo reads are wave-uniform -> scalar loads; r1/r2 coalesced + L2-resident.
// ---------------------------------------------------------------------------
#define ROWS 4
__global__ __launch_bounds__(256) void rho_kernel(
    const float* __restrict__ pooled,   // [B, T*Q]
    const float* __restrict__ r1,       // [448,256]
    const float* __restrict__ rb1,      // [256]
    const float* __restrict__ r2,       // [256,256]
    const float* __restrict__ rb2,      // [256]
    const float* __restrict__ r3,       // [256,10]
    const float* __restrict__ rb3,      // [10]
    float* __restrict__ out)            // [B, C]
{
    const int b0 = blockIdx.x * ROWS;
    const int tid = threadIdx.x;

    const float* tp[ROWS];
#pragma unroll
    for (int r = 0; r < ROWS; ++r) tp[r] = pooled + (size_t)(b0 + r) * TQ;

    float a[ROWS];
#pragma unroll
    for (int r = 0; r < ROWS; ++r) a[r] = rb1[tid];

#pragma unroll 4
    for (int i = 0; i < TQ; ++i) {
        const float rv = r1[i * WF + tid];
#pragma unroll
        for (int r = 0; r < ROWS; ++r) a[r] = fmaf(tp[r][i], rv, a[r]);
    }

    __shared__ float z1[ROWS][WF];
#pragma unroll
    for (int r = 0; r < ROWS; ++r) z1[r][tid] = fmaxf(a[r], 0.0f);
    __syncthreads();

    float a2[ROWS];
#pragma unroll
    for (int r = 0; r < ROWS; ++r) a2[r] = rb2[tid];

#pragma unroll 4
    for (int i = 0; i < WF; ++i) {
        const float rv = r2[i * WF + tid];
#pragma unroll
        for (int r = 0; r < ROWS; ++r) a2[r] = fmaf(z1[r][i], rv, a2[r]);
    }

    __shared__ float z2[ROWS][WF];
#pragma unroll
    for (int r = 0; r < ROWS; ++r) z2[r][tid] = fmaxf(a2[r], 0.0f);
    __syncthreads();

    if (tid < ROWS * CC) {
        const int r = tid / CC;
        const int c = tid % CC;
        float acc = rb3[c];
#pragma unroll 8
        for (int i = 0; i < WF; ++i) acc = fmaf(z2[r][i], r3[i * CC + c], acc);
        out[(size_t)(b0 + r) * CC + c] = acc;
    }
}

// ---------------------------------------------------------------------------
extern "C" void kernel_launch(void* const* d_in, const int* in_sizes, int n_in,
                              void* d_out, int out_size, void* d_ws, size_t ws_size,
                              hipStream_t stream)
{
    const float* diagms = (const float*)d_in[0];
    // d_in[1] = seg_ids (int32) — structurally n/P with equal counts; unused.
    const float* theta  = (const float*)d_in[2];
    const float* w1     = (const float*)d_in[3];
    const float* b1     = (const float*)d_in[4];
    const float* w2     = (const float*)d_in[5];
    const float* b2     = (const float*)d_in[6];
    const float* w3     = (const float*)d_in[7];
    const float* b3     = (const float*)d_in[8];
    const float* r1     = (const float*)d_in[9];
    const float* rb1    = (const float*)d_in[10];
    const float* r2     = (const float*)d_in[11];
    const float* rb2    = (const float*)d_in[12];
    const float* r3     = (const float*)d_in[13];
    const float* rb3    = (const float*)d_in[14];
    float* out = (float*)d_out;

    float* w_buf  = (float*)d_ws;            // [T*N]
    float* pooled = w_buf + (size_t)TT * NN; // [B, T*Q]

    const int total = TT * NN;               // 716800

    // K1: per-point weight MLP
    point_weight_kernel<<<(total + 255) / 256, 256, 0, stream>>>(
        diagms, w1, b1, w2, b2, w3, b3, w_buf, total);

    // K2: gaussian rep + segment mean-pool (writes topo layout)
    rep_pool_kernel<<<TT * BB, 256, 0, stream>>>(diagms, theta, w_buf, pooled);

    // K3: final rho MLP
    rho_kernel<<<BB / ROWS, 256, 0, stream>>>(pooled, r1, rb1, r2, rb2, r3, rb3, out);
}

// Round 4
// 232.253 us; speedup vs baseline: 1.4645x; 1.4645x over previous
//
#include <hip/hip_runtime.h>
#include <hip/hip_bf16.h>
#include <math.h>

// Problem constants (match reference)
#define TT 7
#define BB 512
#define PP 200
#define QQ 64
#define WWH 64
#define WF 256
#define CC 10
#define NN (BB * PP)          // 102400
#define TQ (TT * QQ)          // 448

// ---------------------------------------------------------------------------
// Kernel 1: per-point weight MLP  w = sigmoid(w3 . relu(W2 relu(W1 x + b1) + b2) + b3)
// One thread per (t,n) point.
// Structure: h[64] fully live in regs (compile-time indices only), layer-2 done
// as 2 k-chunks of 32 accumulators (kc loop NOT unrolled -> body fits I$).
// All weight reads are runtime-uniform -> scalar loads (s_load), leaving the
// VALU almost exclusively to the 4096 v_fmac_f32.
// __launch_bounds__(256,4): cap VGPR ~128 so nothing spills (h+acc ~ 110).
// ---------------------------------------------------------------------------
__global__ __launch_bounds__(256, 4) void point_weight_kernel(
    const float* __restrict__ diagms,   // [T*N, 2]
    const float* __restrict__ w1,       // [2,64]
    const float* __restrict__ b1,       // [64]
    const float* __restrict__ w2,       // [64,64]
    const float* __restrict__ b2,       // [64]
    const float* __restrict__ w3,       // [64]
    const float* __restrict__ b3,       // [1]
    float* __restrict__ w_out,          // [T*N]
    int total)
{
    const int idx = blockIdx.x * blockDim.x + threadIdx.x;
    if (idx >= total) return;

    const float2 d = reinterpret_cast<const float2*>(diagms)[idx];
    const float x = d.x, y = d.y;

    // Layer 1: h = relu(x*W1[0,:] + y*W1[1,:] + b1)   (compile-time indexed)
    float h[WWH];
#pragma unroll
    for (int j = 0; j < WWH; ++j) {
        h[j] = fmaxf(fmaf(x, w1[j], fmaf(y, w1[WWH + j], b1[j])), 0.0f);
    }

    // Layer 2 + 3 fused, in two k-chunks of 32.
    float wacc = b3[0];
#pragma unroll 1
    for (int kc = 0; kc < 2; ++kc) {
        const int k0 = kc * 32;
        float acc[32];
#pragma unroll
        for (int k = 0; k < 32; ++k) acc[k] = b2[k0 + k];

#pragma unroll
        for (int j = 0; j < WWH; ++j) {
            const float hj = h[j];
#pragma unroll
            for (int k = 0; k < 32; ++k) {
                acc[k] = fmaf(hj, w2[j * WWH + k0 + k], acc[k]);
            }
        }

#pragma unroll
        for (int k = 0; k < 32; ++k) {
            wacc = fmaf(fmaxf(acc[k], 0.0f), w3[k0 + k], wacc);
        }
    }

    // sigmoid
    w_out[idx] = 1.0f / (1.0f + __expf(-wacc));
}

// ---------------------------------------------------------------------------
// Kernel 2: gaussian rep * weight, mean-pool per segment.
// One block per (t,b) segment of P=200 points. 256 thr = 64 q  x  4 groups.
// exp(-50*d2) computed as exp2(d2 * -50/ln2) -> single v_exp_f32.
// Writes pooled directly in topo layout [B, T*Q].
// ---------------------------------------------------------------------------
#define NEG50_OVER_LN2 (-72.13475204444817f)

__global__ __launch_bounds__(256) void rep_pool_kernel(
    const float* __restrict__ diagms,   // [T*N, 2]
    const float* __restrict__ theta,    // [Q,2]
    const float* __restrict__ w_in,     // [T*N]
    float* __restrict__ pooled)         // [B, T*Q]
{
    const int bid = blockIdx.x;         // t*B + b
    const int t = bid >> 9;             // / 512
    const int b = bid & (BB - 1);       // % 512
    const int tid = threadIdx.x;

    __shared__ float px[PP];
    __shared__ float py[PP];
    __shared__ float wv[PP];

    if (tid < PP) {
        const int n = t * NN + b * PP + tid;
        const float2 d = reinterpret_cast<const float2*>(diagms)[n];
        px[tid] = d.x;
        py[tid] = d.y;
        wv[tid] = w_in[n];
    }
    __syncthreads();

    const int q = tid & (QQ - 1);
    const int g = tid >> 6;             // 0..3, uniform per wave
    const float2 th = reinterpret_cast<const float2*>(theta)[q];
    const float tx = th.x;
    const float ty = th.y;

    float acc = 0.0f;
    const int p0 = g * (PP / 4);
#pragma unroll 5
    for (int p = p0; p < p0 + PP / 4; ++p) {
        const float dx = px[p] - tx;
        const float dy = py[p] - ty;
        acc = fmaf(wv[p], exp2f(fmaf(dx, dx, dy * dy) * NEG50_OVER_LN2), acc);
    }

    __shared__ float part[4][QQ];
    part[g][q] = acc;
    __syncthreads();

    if (tid < QQ) {
        const float s = (part[0][tid] + part[1][tid]) + (part[2][tid] + part[3][tid]);
        pooled[b * TQ + t * QQ + tid] = s * (1.0f / (float)PP);
    }
}

// ---------------------------------------------------------------------------
// Kernel 3: rho MLP.  out = relu(relu(topo@r1+rb1)@r2+rb2)@r3+rb3
// 2 batch rows per block, 256 blocks, 512 threads = 2 i-groups x 256 features.
// Splitting the i-loop halves the serial chain and doubles resident waves
// (2 blocks/CU) vs the round-0 version (0.5 blocks/CU, zero latency hiding).
// ---------------------------------------------------------------------------
#define K3_ROWS 2
__global__ __launch_bounds__(512) void rho_kernel(
    const float* __restrict__ pooled,   // [B, T*Q]
    const float* __restrict__ r1,       // [448,256]
    const float* __restrict__ rb1,      // [256]
    const float* __restrict__ r2,       // [256,256]
    const float* __restrict__ rb2,      // [256]
    const float* __restrict__ r3,       // [256,10]
    const float* __restrict__ rb3,      // [10]
    float* __restrict__ out)            // [B, C]
{
    const int b0 = blockIdx.x * K3_ROWS;
    const int tid = threadIdx.x;        // 0..511
    const int k = tid & (WF - 1);       // feature 0..255
    const int g = tid >> 8;             // i-group 0/1

    __shared__ float z1[K3_ROWS][WF];
    __shared__ float z2[K3_ROWS][WF];
    __shared__ float part[2][K3_ROWS][WF];

    const float* __restrict__ tp0 = pooled + (size_t)b0 * TQ;
    const float* __restrict__ tp1 = tp0 + TQ;

    // ---- layer 1: [2 rows] x [448 -> 256], i split across 2 groups
    float a0 = 0.0f, a1 = 0.0f;
    {
        const int i0 = g * (TQ / 2);
#pragma unroll 4
        for (int i = i0; i < i0 + TQ / 2; ++i) {
            const float rv = r1[i * WF + k];
            a0 = fmaf(tp0[i], rv, a0);
            a1 = fmaf(tp1[i], rv, a1);
        }
    }
    part[g][0][k] = a0;
    part[g][1][k] = a1;
    __syncthreads();
    if (g == 0) {
        z1[0][k] = fmaxf(part[0][0][k] + part[1][0][k] + rb1[k], 0.0f);
        z1[1][k] = fmaxf(part[0][1][k] + part[1][1][k] + rb1[k], 0.0f);
    }
    __syncthreads();

    // ---- layer 2: [2 rows] x [256 -> 256]
    float c0 = 0.0f, c1 = 0.0f;
    {
        const int i0 = g * (WF / 2);
#pragma unroll 4
        for (int i = i0; i < i0 + WF / 2; ++i) {
            const float rv = r2[i * WF + k];
            c0 = fmaf(z1[0][i], rv, c0);
            c1 = fmaf(z1[1][i], rv, c1);
        }
    }
    part[g][0][k] = c0;
    part[g][1][k] = c1;
    __syncthreads();
    if (g == 0) {
        z2[0][k] = fmaxf(part[0][0][k] + part[1][0][k] + rb2[k], 0.0f);
        z2[1][k] = fmaxf(part[0][1][k] + part[1][1][k] + rb2[k], 0.0f);
    }
    __syncthreads();

    // ---- layer 3: [2 rows] x [256 -> 10]
    if (tid < K3_ROWS * CC) {
        const int r = tid / CC;
        const int c = tid % CC;
        float acc = rb3[c];
#pragma unroll 8
        for (int i = 0; i < WF; ++i) acc = fmaf(z2[r][i], r3[i * CC + c], acc);
        out[(size_t)(b0 + r) * CC + c] = acc;
    }
}

// ---------------------------------------------------------------------------
extern "C" void kernel_launch(void* const* d_in, const int* in_sizes, int n_in,
                              void* d_out, int out_size, void* d_ws, size_t ws_size,
                              hipStream_t stream)
{
    const float* diagms = (const float*)d_in[0];
    // d_in[1] = seg_ids (int32) — structurally n/P with equal counts; unused.
    const float* theta  = (const float*)d_in[2];
    const float* w1     = (const float*)d_in[3];
    const float* b1     = (const float*)d_in[4];
    const float* w2     = (const float*)d_in[5];
    const float* b2     = (const float*)d_in[6];
    const float* w3     = (const float*)d_in[7];
    const float* b3     = (const float*)d_in[8];
    const float* r1     = (const float*)d_in[9];
    const float* rb1    = (const float*)d_in[10];
    const float* r2     = (const float*)d_in[11];
    const float* rb2    = (const float*)d_in[12];
    const float* r3     = (const float*)d_in[13];
    const float* rb3    = (const float*)d_in[14];
    float* out = (float*)d_out;

    float* w_buf  = (float*)d_ws;            // [T*N]
    float* pooled = w_buf + (size_t)TT * NN; // [B, T*Q]

    const int total = TT * NN;               // 716800

    // K1: per-point weight MLP
    point_weight_kernel<<<(total + 255) / 256, 256, 0, stream>>>(
        diagms, w1, b1, w2, b2, w3, b3, w_buf, total);

    // K2: gaussian rep + segment mean-pool (writes topo layout)
    rep_pool_kernel<<<TT * BB, 256, 0, stream>>>(diagms, theta, w_buf, pooled);

    // K3: final rho MLP
    rho_kernel<<<BB / K3_ROWS, 512, 0, stream>>>(pooled, r1, rb1, r2, rb2, r3, rb3, out);
}

// Round 5
// 152.387 us; speedup vs baseline: 2.2321x; 1.5241x over previous
//
#include <hip/hip_runtime.h>
#include <hip/hip_bf16.h>
#include <math.h>

// Problem constants (match reference)
#define TT 7
#define BB 512
#define PP 200
#define QQ 64
#define WWH 64
#define WF 256
#define CC 10
#define NN (BB * PP)          // 102400
#define TQ (TT * QQ)          // 448

typedef __attribute__((ext_vector_type(8))) short short8;
typedef __attribute__((ext_vector_type(4))) float f32x4;

static __device__ __forceinline__ unsigned short f2bf(float f) {
    __hip_bfloat16 b = __float2bfloat16(f);   // RNE
    return *reinterpret_cast<unsigned short*>(&b);
}

// ---------------------------------------------------------------------------
// Kernel 1 (MFMA): per-point weight MLP.
// 256 points/block, 4 waves, each wave owns 64 points.
// Layer 1 (2->64) on VALU -> H bf16 in LDS (XOR-swizzled 16B slots).
// Layer 2 (64->64) = mfma_f32_16x16x32_bf16: per wave 4 Mtiles x 4 Ntiles x 2 Ksteps.
//   A: lane l holds H[row=l&15][k=(l>>4)*8..+7] (16B contiguous, swizzled slot).
//   B: lane l holds W2[k=(l>>4)*8..+7][n=l&15]  -> staged as W2T[n][k] contiguous.
//   C/D: col=lane&15, row=(lane>>4)*4+reg  [verified m89/m91].
// Layer 3 (64->1) + b2 + relu + w3 + sigmoid fused in epilogue via
// 16-lane shfl_xor reduce.
// LDS: H 32KB + W2T 8KB = 40KB -> 4 blocks/CU.
// ---------------------------------------------------------------------------
__global__ __launch_bounds__(256, 4) void point_weight_kernel(
    const float* __restrict__ diagms,   // [T*N, 2]
    const float* __restrict__ w1,       // [2,64]
    const float* __restrict__ b1,       // [64]
    const float* __restrict__ w2,       // [64,64]
    const float* __restrict__ b2,       // [64]
    const float* __restrict__ w3,       // [64]
    const float* __restrict__ b3,       // [1]
    float* __restrict__ w_out)          // [T*N]
{
    __shared__ unsigned short Hl[256 * 64];    // [point][k] bf16, swizzled
    __shared__ unsigned short W2T[64 * 64];    // [n][k]     bf16, swizzled

    const int tid  = threadIdx.x;
    const int lane = tid & 63;
    const int wv   = tid >> 6;

    // ---- stage W2T = w2^T as bf16, swizzled (one-time, cooperative) --------
    {
        const int n  = tid & 63;
        const int j0 = (tid >> 6) * 16;
#pragma unroll
        for (int jj = 0; jj < 16; ++jj) {
            const int j = j0 + jj;
            // coalesced: fixed j, consecutive n read consecutive floats
            const float v = w2[j * WWH + n];
            // W2T[n][j], 16B slot = j>>3, swizzled slot ^= (n&7)
            const int off = n * 64 + ((((j >> 3) ^ (n & 7))) << 3) + (j & 7);
            W2T[off] = f2bf(v);
        }
    }

    // ---- layer 1: h = relu(x*W1[0,:] + y*W1[1,:] + b1) -> Hl row (bf16) ----
    {
        const int p = tid;  // block-local point
        const float2 d = reinterpret_cast<const float2*>(diagms)[(size_t)blockIdx.x * 256 + p];
        const float x = d.x, y = d.y;
        uint4* Hrow = reinterpret_cast<uint4*>(Hl);
#pragma unroll
        for (int i = 0; i < 8; ++i) {          // 8 groups of 8 k
            unsigned int pk[4];
#pragma unroll
            for (int e = 0; e < 4; ++e) {
                const int j = i * 8 + 2 * e;
                const float h0 = fmaxf(fmaf(x, w1[j],     fmaf(y, w1[WWH + j],     b1[j])),     0.0f);
                const float h1 = fmaxf(fmaf(x, w1[j + 1], fmaf(y, w1[WWH + j + 1], b1[j + 1])), 0.0f);
                pk[e] = (unsigned int)f2bf(h0) | ((unsigned int)f2bf(h1) << 16);
            }
            uint4 v; v.x = pk[0]; v.y = pk[1]; v.z = pk[2]; v.w = pk[3];
            Hrow[p * 8 + (i ^ (p & 7))] = v;   // swizzled 16B slot
        }
    }

    __syncthreads();   // W2T + H visible to all

    // ---- per-lane constants for epilogue ----------------------------------
    float b2v[4], w3v[4];
#pragma unroll
    for (int nt = 0; nt < 4; ++nt) {
        b2v[nt] = b2[nt * 16 + (lane & 15)];
        w3v[nt] = w3[nt * 16 + (lane & 15)];
    }
    const float b3s = b3[0];

    // ---- B fragments: 2 ksteps x 4 ntiles, reused across all Mtiles -------
    short8 bf[2][4];
#pragma unroll
    for (int s = 0; s < 2; ++s) {
#pragma unroll
        for (int nt = 0; nt < 4; ++nt) {
            const int n = nt * 16 + (lane & 15);
            const int slot = ((lane >> 4) + s * 4) ^ (lane & 7);
            bf[s][nt] = reinterpret_cast<const short8*>(W2T)[n * 8 + slot];
        }
    }

    const int wave_p0 = wv * 64;
    const size_t out_base = (size_t)blockIdx.x * 256;

#pragma unroll 1
    for (int m = 0; m < 4; ++m) {
        f32x4 acc[4];
#pragma unroll
        for (int nt = 0; nt < 4; ++nt) acc[nt] = (f32x4){0.f, 0.f, 0.f, 0.f};

#pragma unroll
        for (int s = 0; s < 2; ++s) {
            const int p = wave_p0 + m * 16 + (lane & 15);
            const int slot = ((lane >> 4) + s * 4) ^ (lane & 7);
            const short8 af = reinterpret_cast<const short8*>(Hl)[p * 8 + slot];
#pragma unroll
            for (int nt = 0; nt < 4; ++nt) {
                acc[nt] = __builtin_amdgcn_mfma_f32_16x16x32_bf16(af, bf[s][nt], acc[nt], 0, 0, 0);
            }
        }

        // ---- epilogue: +b2, relu, dot w3, 16-lane reduce, sigmoid ---------
        float sum0 = 0.f, sum1 = 0.f, sum2 = 0.f, sum3 = 0.f;
#pragma unroll
        for (int nt = 0; nt < 4; ++nt) {
            sum0 = fmaf(fmaxf(acc[nt][0] + b2v[nt], 0.f), w3v[nt], sum0);
            sum1 = fmaf(fmaxf(acc[nt][1] + b2v[nt], 0.f), w3v[nt], sum1);
            sum2 = fmaf(fmaxf(acc[nt][2] + b2v[nt], 0.f), w3v[nt], sum2);
            sum3 = fmaf(fmaxf(acc[nt][3] + b2v[nt], 0.f), w3v[nt], sum3);
        }
#pragma unroll
        for (int off = 1; off < 16; off <<= 1) {
            sum0 += __shfl_xor(sum0, off, 64);
            sum1 += __shfl_xor(sum1, off, 64);
            sum2 += __shfl_xor(sum2, off, 64);
            sum3 += __shfl_xor(sum3, off, 64);
        }
        const int r_sel = lane & 15;
        if (r_sel < 4) {
            const float sv = (r_sel == 0) ? sum0 : (r_sel == 1) ? sum1
                           : (r_sel == 2) ? sum2 : sum3;           // static select (rule #20)
            const float wa = sv + b3s;
            const float wsig = 1.0f / (1.0f + __expf(-wa));
            const int prow = wave_p0 + m * 16 + ((lane >> 4) << 2) + r_sel;
            w_out[out_base + prow] = wsig;
        }
    }
}

// ---------------------------------------------------------------------------
// Kernel 2: gaussian rep * weight, mean-pool per segment. (unchanged)
// ---------------------------------------------------------------------------
#define NEG50_OVER_LN2 (-72.13475204444817f)

__global__ __launch_bounds__(256) void rep_pool_kernel(
    const float* __restrict__ diagms,   // [T*N, 2]
    const float* __restrict__ theta,    // [Q,2]
    const float* __restrict__ w_in,     // [T*N]
    float* __restrict__ pooled)         // [B, T*Q]
{
    const int bid = blockIdx.x;         // t*B + b
    const int t = bid >> 9;             // / 512
    const int b = bid & (BB - 1);       // % 512
    const int tid = threadIdx.x;

    __shared__ float px[PP];
    __shared__ float py[PP];
    __shared__ float wv[PP];

    if (tid < PP) {
        const int n = t * NN + b * PP + tid;
        const float2 d = reinterpret_cast<const float2*>(diagms)[n];
        px[tid] = d.x;
        py[tid] = d.y;
        wv[tid] = w_in[n];
    }
    __syncthreads();

    const int q = tid & (QQ - 1);
    const int g = tid >> 6;             // 0..3, uniform per wave
    const float2 th = reinterpret_cast<const float2*>(theta)[q];
    const float tx = th.x;
    const float ty = th.y;

    float acc = 0.0f;
    const int p0 = g * (PP / 4);
#pragma unroll 5
    for (int p = p0; p < p0 + PP / 4; ++p) {
        const float dx = px[p] - tx;
        const float dy = py[p] - ty;
        acc = fmaf(wv[p], exp2f(fmaf(dx, dx, dy * dy) * NEG50_OVER_LN2), acc);
    }

    __shared__ float part[4][QQ];
    part[g][q] = acc;
    __syncthreads();

    if (tid < QQ) {
        const float s = (part[0][tid] + part[1][tid]) + (part[2][tid] + part[3][tid]);
        pooled[b * TQ + t * QQ + tid] = s * (1.0f / (float)PP);
    }
}

// ---------------------------------------------------------------------------
// Kernel 3: rho MLP. (unchanged)
// ---------------------------------------------------------------------------
#define K3_ROWS 2
__global__ __launch_bounds__(512) void rho_kernel(
    const float* __restrict__ pooled,   // [B, T*Q]
    const float* __restrict__ r1,       // [448,256]
    const float* __restrict__ rb1,      // [256]
    const float* __restrict__ r2,       // [256,256]
    const float* __restrict__ rb2,      // [256]
    const float* __restrict__ r3,       // [256,10]
    const float* __restrict__ rb3,      // [10]
    float* __restrict__ out)            // [B, C]
{
    const int b0 = blockIdx.x * K3_ROWS;
    const int tid = threadIdx.x;        // 0..511
    const int k = tid & (WF - 1);       // feature 0..255
    const int g = tid >> 8;             // i-group 0/1

    __shared__ float z1[K3_ROWS][WF];
    __shared__ float z2[K3_ROWS][WF];
    __shared__ float part[2][K3_ROWS][WF];

    const float* __restrict__ tp0 = pooled + (size_t)b0 * TQ;
    const float* __restrict__ tp1 = tp0 + TQ;

    // ---- layer 1: [2 rows] x [448 -> 256], i split across 2 groups
    float a0 = 0.0f, a1 = 0.0f;
    {
        const int i0 = g * (TQ / 2);
#pragma unroll 4
        for (int i = i0; i < i0 + TQ / 2; ++i) {
            const float rv = r1[i * WF + k];
            a0 = fmaf(tp0[i], rv, a0);
            a1 = fmaf(tp1[i], rv, a1);
        }
    }
    part[g][0][k] = a0;
    part[g][1][k] = a1;
    __syncthreads();
    if (g == 0) {
        z1[0][k] = fmaxf(part[0][0][k] + part[1][0][k] + rb1[k], 0.0f);
        z1[1][k] = fmaxf(part[0][1][k] + part[1][1][k] + rb1[k], 0.0f);
    }
    __syncthreads();

    // ---- layer 2: [2 rows] x [256 -> 256]
    float c0 = 0.0f, c1 = 0.0f;
    {
        const int i0 = g * (WF / 2);
#pragma unroll 4
        for (int i = i0; i < i0 + WF / 2; ++i) {
            const float rv = r2[i * WF + k];
            c0 = fmaf(z1[0][i], rv, c0);
            c1 = fmaf(z1[1][i], rv, c1);
        }
    }
    part[g][0][k] = c0;
    part[g][1][k] = c1;
    __syncthreads();
    if (g == 0) {
        z2[0][k] = fmaxf(part[0][0][k] + part[1][0][k] + rb2[k], 0.0f);
        z2[1][k] = fmaxf(part[0][1][k] + part[1][1][k] + rb2[k], 0.0f);
    }
    __syncthreads();

    // ---- layer 3: [2 rows] x [256 -> 10]
    if (tid < K3_ROWS * CC) {
        const int r = tid / CC;
        const int c = tid % CC;
        float acc = rb3[c];
#pragma unroll 8
        for (int i = 0; i < WF; ++i) acc = fmaf(z2[r][i], r3[i * CC + c], acc);
        out[(size_t)(b0 + r) * CC + c] = acc;
    }
}

// ---------------------------------------------------------------------------
extern "C" void kernel_launch(void* const* d_in, const int* in_sizes, int n_in,
                              void* d_out, int out_size, void* d_ws, size_t ws_size,
                              hipStream_t stream)
{
    const float* diagms = (const float*)d_in[0];
    // d_in[1] = seg_ids (int32) — structurally n/P with equal counts; unused.
    const float* theta  = (const float*)d_in[2];
    const float* w1     = (const float*)d_in[3];
    const float* b1     = (const float*)d_in[4];
    const float* w2     = (const float*)d_in[5];
    const float* b2     = (const float*)d_in[6];
    const float* w3     = (const float*)d_in[7];
    const float* b3     = (const float*)d_in[8];
    const float* r1     = (const float*)d_in[9];
    const float* rb1    = (const float*)d_in[10];
    const float* r2     = (const float*)d_in[11];
    const float* rb2    = (const float*)d_in[12];
    const float* r3     = (const float*)d_in[13];
    const float* rb3    = (const float*)d_in[14];
    float* out = (float*)d_out;

    float* w_buf  = (float*)d_ws;            // [T*N]
    float* pooled = w_buf + (size_t)TT * NN; // [B, T*Q]

    const int total = TT * NN;               // 716800

    // K1: per-point weight MLP (MFMA)  — 2800 blocks x 256 points
    point_weight_kernel<<<total / 256, 256, 0, stream>>>(
        diagms, w1, b1, w2, b2, w3, b3, w_buf);

    // K2: gaussian rep + segment mean-pool (writes topo layout)
    rep_pool_kernel<<<TT * BB, 256, 0, stream>>>(diagms, theta, w_buf, pooled);

    // K3: final rho MLP
    rho_kernel<<<BB / K3_ROWS, 512, 0, stream>>>(pooled, r1, rb1, r2, rb2, r3, rb3, out);
}

// Round 6
// 145.440 us; speedup vs baseline: 2.3387x; 1.0478x over previous
//
#include <hip/hip_runtime.h>
#include <hip/hip_bf16.h>
#include <math.h>

// Problem constants (match reference)
#define TT 7
#define BB 512
#define PP 200
#define QQ 64
#define WWH 64
#define WF 256
#define CC 10
#define NN (BB * PP)          // 102400
#define TQ (TT * QQ)          // 448

typedef __attribute__((ext_vector_type(8))) short short8;
typedef __attribute__((ext_vector_type(4))) float f32x4;

static __device__ __forceinline__ unsigned short f2bf(float f) {
    __hip_bfloat16 b = __float2bfloat16(f);   // RNE
    return *reinterpret_cast<unsigned short*>(&b);
}

// ---------------------------------------------------------------------------
// Kernel 1 (MFMA): per-point weight MLP. (unchanged from round 5)
// ---------------------------------------------------------------------------
__global__ __launch_bounds__(256, 4) void point_weight_kernel(
    const float* __restrict__ diagms,   // [T*N, 2]
    const float* __restrict__ w1,       // [2,64]
    const float* __restrict__ b1,       // [64]
    const float* __restrict__ w2,       // [64,64]
    const float* __restrict__ b2,       // [64]
    const float* __restrict__ w3,       // [64]
    const float* __restrict__ b3,       // [1]
    float* __restrict__ w_out)          // [T*N]
{
    __shared__ unsigned short Hl[256 * 64];    // [point][k] bf16, swizzled
    __shared__ unsigned short W2T[64 * 64];    // [n][k]     bf16, swizzled

    const int tid  = threadIdx.x;
    const int lane = tid & 63;
    const int wv   = tid >> 6;

    // ---- stage W2T = w2^T as bf16, swizzled (one-time, cooperative) --------
    {
        const int n  = tid & 63;
        const int j0 = (tid >> 6) * 16;
#pragma unroll
        for (int jj = 0; jj < 16; ++jj) {
            const int j = j0 + jj;
            const float v = w2[j * WWH + n];
            const int off = n * 64 + ((((j >> 3) ^ (n & 7))) << 3) + (j & 7);
            W2T[off] = f2bf(v);
        }
    }

    // ---- layer 1: h = relu(x*W1[0,:] + y*W1[1,:] + b1) -> Hl row (bf16) ----
    {
        const int p = tid;  // block-local point
        const float2 d = reinterpret_cast<const float2*>(diagms)[(size_t)blockIdx.x * 256 + p];
        const float x = d.x, y = d.y;
        uint4* Hrow = reinterpret_cast<uint4*>(Hl);
#pragma unroll
        for (int i = 0; i < 8; ++i) {          // 8 groups of 8 k
            unsigned int pk[4];
#pragma unroll
            for (int e = 0; e < 4; ++e) {
                const int j = i * 8 + 2 * e;
                const float h0 = fmaxf(fmaf(x, w1[j],     fmaf(y, w1[WWH + j],     b1[j])),     0.0f);
                const float h1 = fmaxf(fmaf(x, w1[j + 1], fmaf(y, w1[WWH + j + 1], b1[j + 1])), 0.0f);
                pk[e] = (unsigned int)f2bf(h0) | ((unsigned int)f2bf(h1) << 16);
            }
            uint4 v; v.x = pk[0]; v.y = pk[1]; v.z = pk[2]; v.w = pk[3];
            Hrow[p * 8 + (i ^ (p & 7))] = v;   // swizzled 16B slot
        }
    }

    __syncthreads();   // W2T + H visible to all

    // ---- per-lane constants for epilogue ----------------------------------
    float b2v[4], w3v[4];
#pragma unroll
    for (int nt = 0; nt < 4; ++nt) {
        b2v[nt] = b2[nt * 16 + (lane & 15)];
        w3v[nt] = w3[nt * 16 + (lane & 15)];
    }
    const float b3s = b3[0];

    // ---- B fragments: 2 ksteps x 4 ntiles, reused across all Mtiles -------
    short8 bf[2][4];
#pragma unroll
    for (int s = 0; s < 2; ++s) {
#pragma unroll
        for (int nt = 0; nt < 4; ++nt) {
            const int n = nt * 16 + (lane & 15);
            const int slot = ((lane >> 4) + s * 4) ^ (lane & 7);
            bf[s][nt] = reinterpret_cast<const short8*>(W2T)[n * 8 + slot];
        }
    }

    const int wave_p0 = wv * 64;
    const size_t out_base = (size_t)blockIdx.x * 256;

#pragma unroll 1
    for (int m = 0; m < 4; ++m) {
        f32x4 acc[4];
#pragma unroll
        for (int nt = 0; nt < 4; ++nt) acc[nt] = (f32x4){0.f, 0.f, 0.f, 0.f};

#pragma unroll
        for (int s = 0; s < 2; ++s) {
            const int p = wave_p0 + m * 16 + (lane & 15);
            const int slot = ((lane >> 4) + s * 4) ^ (lane & 7);
            const short8 af = reinterpret_cast<const short8*>(Hl)[p * 8 + slot];
#pragma unroll
            for (int nt = 0; nt < 4; ++nt) {
                acc[nt] = __builtin_amdgcn_mfma_f32_16x16x32_bf16(af, bf[s][nt], acc[nt], 0, 0, 0);
            }
        }

        // ---- epilogue: +b2, relu, dot w3, 16-lane reduce, sigmoid ---------
        float sum0 = 0.f, sum1 = 0.f, sum2 = 0.f, sum3 = 0.f;
#pragma unroll
        for (int nt = 0; nt < 4; ++nt) {
            sum0 = fmaf(fmaxf(acc[nt][0] + b2v[nt], 0.f), w3v[nt], sum0);
            sum1 = fmaf(fmaxf(acc[nt][1] + b2v[nt], 0.f), w3v[nt], sum1);
            sum2 = fmaf(fmaxf(acc[nt][2] + b2v[nt], 0.f), w3v[nt], sum2);
            sum3 = fmaf(fmaxf(acc[nt][3] + b2v[nt], 0.f), w3v[nt], sum3);
        }
#pragma unroll
        for (int off = 1; off < 16; off <<= 1) {
            sum0 += __shfl_xor(sum0, off, 64);
            sum1 += __shfl_xor(sum1, off, 64);
            sum2 += __shfl_xor(sum2, off, 64);
            sum3 += __shfl_xor(sum3, off, 64);
        }
        const int r_sel = lane & 15;
        if (r_sel < 4) {
            const float sv = (r_sel == 0) ? sum0 : (r_sel == 1) ? sum1
                           : (r_sel == 2) ? sum2 : sum3;           // static select (rule #20)
            const float wa = sv + b3s;
            const float wsig = 1.0f / (1.0f + __expf(-wa));
            const int prow = wave_p0 + m * 16 + ((lane >> 4) << 2) + r_sel;
            w_out[out_base + prow] = wsig;
        }
    }
}

// ---------------------------------------------------------------------------
// Kernel 2: gaussian rep * weight, mean-pool per segment. (unchanged)
// ---------------------------------------------------------------------------
#define NEG50_OVER_LN2 (-72.13475204444817f)

__global__ __launch_bounds__(256) void rep_pool_kernel(
    const float* __restrict__ diagms,   // [T*N, 2]
    const float* __restrict__ theta,    // [Q,2]
    const float* __restrict__ w_in,     // [T*N]
    float* __restrict__ pooled)         // [B, T*Q]
{
    const int bid = blockIdx.x;         // t*B + b
    const int t = bid >> 9;             // / 512
    const int b = bid & (BB - 1);       // % 512
    const int tid = threadIdx.x;

    __shared__ float px[PP];
    __shared__ float py[PP];
    __shared__ float wv[PP];

    if (tid < PP) {
        const int n = t * NN + b * PP + tid;
        const float2 d = reinterpret_cast<const float2*>(diagms)[n];
        px[tid] = d.x;
        py[tid] = d.y;
        wv[tid] = w_in[n];
    }
    __syncthreads();

    const int q = tid & (QQ - 1);
    const int g = tid >> 6;             // 0..3, uniform per wave
    const float2 th = reinterpret_cast<const float2*>(theta)[q];
    const float tx = th.x;
    const float ty = th.y;

    float acc = 0.0f;
    const int p0 = g * (PP / 4);
#pragma unroll 5
    for (int p = p0; p < p0 + PP / 4; ++p) {
        const float dx = px[p] - tx;
        const float dy = py[p] - ty;
        acc = fmaf(wv[p], exp2f(fmaf(dx, dx, dy * dy) * NEG50_OVER_LN2), acc);
    }

    __shared__ float part[4][QQ];
    part[g][q] = acc;
    __syncthreads();

    if (tid < QQ) {
        const float s = (part[0][tid] + part[1][tid]) + (part[2][tid] + part[3][tid]);
        pooled[b * TQ + t * QQ + tid] = s * (1.0f / (float)PP);
    }
}

// ---------------------------------------------------------------------------
// Kernel 3 (v2): rho MLP, latency-pipelined.
// 2 rows/block, 256 blocks x 256 threads (thread = output feature).
// Round-5 failure mode: VGPR_Count=16 -> compiler serialized r1/r2 column
// loads (~200cy L2 latency each, 448 of them = ~37us). Fix:
//   - __launch_bounds__(256,2): open register budget (~128 VGPR)
//   - manual register double-buffer: two 8-wide load batches, ~16 loads in
//     flight while 16 FMAs retire
//   - topo rows staged in LDS (broadcast reads, no global re-reads)
//   - layer 3: all-thread outer product + shfl_xor reduce (old version: 20
//     threads x 256 serial strided loads = pure latency tail)
// ---------------------------------------------------------------------------
#define K3_ROWS 2
__global__ __launch_bounds__(256, 2) void rho_kernel(
    const float* __restrict__ pooled,   // [B, T*Q]
    const float* __restrict__ r1,       // [448,256]
    const float* __restrict__ rb1,      // [256]
    const float* __restrict__ r2,       // [256,256]
    const float* __restrict__ rb2,      // [256]
    const float* __restrict__ r3,       // [256,10]
    const float* __restrict__ rb3,      // [10]
    float* __restrict__ out)            // [B, C]
{
    const int b0 = blockIdx.x * K3_ROWS;
    const int tid = threadIdx.x;        // 0..255 = feature k

    __shared__ float tp[K3_ROWS * TQ];  // 896 floats (rows contiguous)
    __shared__ float z1[K3_ROWS][WF];
    __shared__ float z2[K3_ROWS][WF];
    __shared__ float red[4][K3_ROWS][CC];

    // ---- stage the 2 topo rows (flat, coalesced) --------------------------
    {
        const float* src = pooled + (size_t)b0 * TQ;
#pragma unroll
        for (int j = 0; j < K3_ROWS * TQ; j += 256) {
            const int idx = j + tid;
            if (idx < K3_ROWS * TQ) tp[idx] = src[idx];
        }
    }
    __syncthreads();

    // ---- layer 1: 448-deep, double-buffered 8-wide column loads -----------
    {
        float acc0 = rb1[tid], acc1 = rb1[tid];
        const float* r1c = r1 + tid;
        float rv0[8], rv1[8];
#pragma unroll
        for (int e = 0; e < 8; ++e) rv0[e] = r1c[e * WF];
#pragma unroll 1
        for (int i0 = 0; i0 < TQ; i0 += 16) {
#pragma unroll
            for (int e = 0; e < 8; ++e) rv1[e] = r1c[(i0 + 8 + e) * WF];
#pragma unroll
            for (int e = 0; e < 8; ++e) {
                acc0 = fmaf(tp[i0 + e],      rv0[e], acc0);
                acc1 = fmaf(tp[TQ + i0 + e], rv0[e], acc1);
            }
            if (i0 + 16 < TQ) {
#pragma unroll
                for (int e = 0; e < 8; ++e) rv0[e] = r1c[(i0 + 16 + e) * WF];
            }
#pragma unroll
            for (int e = 0; e < 8; ++e) {
                acc0 = fmaf(tp[i0 + 8 + e],      rv1[e], acc0);
                acc1 = fmaf(tp[TQ + i0 + 8 + e], rv1[e], acc1);
            }
        }
        z1[0][tid] = fmaxf(acc0, 0.0f);
        z1[1][tid] = fmaxf(acc1, 0.0f);
    }
    __syncthreads();

    // ---- layer 2: 256-deep, same pipeline ---------------------------------
    {
        float acc0 = rb2[tid], acc1 = rb2[tid];
        const float* r2c = r2 + tid;
        float rv0[8], rv1[8];
#pragma unroll
        for (int e = 0; e < 8; ++e) rv0[e] = r2c[e * WF];
#pragma unroll 1
        for (int i0 = 0; i0 < WF; i0 += 16) {
#pragma unroll
            for (int e = 0; e < 8; ++e) rv1[e] = r2c[(i0 + 8 + e) * WF];
#pragma unroll
            for (int e = 0; e < 8; ++e) {
                acc0 = fmaf(z1[0][i0 + e], rv0[e], acc0);
                acc1 = fmaf(z1[1][i0 + e], rv0[e], acc1);
            }
            if (i0 + 16 < WF) {
#pragma unroll
                for (int e = 0; e < 8; ++e) rv0[e] = r2c[(i0 + 16 + e) * WF];
            }
#pragma unroll
            for (int e = 0; e < 8; ++e) {
                acc0 = fmaf(z1[0][i0 + 8 + e], rv1[e], acc0);
                acc1 = fmaf(z1[1][i0 + 8 + e], rv1[e], acc1);
            }
        }
        z2[0][tid] = fmaxf(acc0, 0.0f);
        z2[1][tid] = fmaxf(acc1, 0.0f);
    }
    __syncthreads();

    // ---- layer 3: outer product + wave reduce -----------------------------
    {
        const int lane = tid & 63;
        const int wvi  = tid >> 6;
        const float za = z2[0][tid];
        const float zb = z2[1][tid];
        float p0[CC], p1[CC];
#pragma unroll
        for (int c = 0; c < CC; ++c) {
            const float rc = r3[tid * CC + c];   // contiguous across threads
            p0[c] = za * rc;
            p1[c] = zb * rc;
        }
#pragma unroll
        for (int off = 32; off >= 1; off >>= 1) {
#pragma unroll
            for (int c = 0; c < CC; ++c) {
                p0[c] += __shfl_xor(p0[c], off, 64);
                p1[c] += __shfl_xor(p1[c], off, 64);
            }
        }
        if (lane == 0) {
#pragma unroll
            for (int c = 0; c < CC; ++c) {
                red[wvi][0][c] = p0[c];
                red[wvi][1][c] = p1[c];
            }
        }
        __syncthreads();
        if (tid < K3_ROWS * CC) {
            const int r = tid / CC;
            const int c = tid % CC;
            out[(size_t)(b0 + r) * CC + c] =
                red[0][r][c] + red[1][r][c] + red[2][r][c] + red[3][r][c] + rb3[c];
        }
    }
}

// ---------------------------------------------------------------------------
extern "C" void kernel_launch(void* const* d_in, const int* in_sizes, int n_in,
                              void* d_out, int out_size, void* d_ws, size_t ws_size,
                              hipStream_t stream)
{
    const float* diagms = (const float*)d_in[0];
    // d_in[1] = seg_ids (int32) — structurally n/P with equal counts; unused.
    const float* theta  = (const float*)d_in[2];
    const float* w1     = (const float*)d_in[3];
    const float* b1     = (const float*)d_in[4];
    const float* w2     = (const float*)d_in[5];
    const float* b2     = (const float*)d_in[6];
    const float* w3     = (const float*)d_in[7];
    const float* b3     = (const float*)d_in[8];
    const float* r1     = (const float*)d_in[9];
    const float* rb1    = (const float*)d_in[10];
    const float* r2     = (const float*)d_in[11];
    const float* rb2    = (const float*)d_in[12];
    const float* r3     = (const float*)d_in[13];
    const float* rb3    = (const float*)d_in[14];
    float* out = (float*)d_out;

    float* w_buf  = (float*)d_ws;            // [T*N]
    float* pooled = w_buf + (size_t)TT * NN; // [B, T*Q]

    const int total = TT * NN;               // 716800

    // K1: per-point weight MLP (MFMA)  — 2800 blocks x 256 points
    point_weight_kernel<<<total / 256, 256, 0, stream>>>(
        diagms, w1, b1, w2, b2, w3, b3, w_buf);

    // K2: gaussian rep + segment mean-pool (writes topo layout)
    rep_pool_kernel<<<TT * BB, 256, 0, stream>>>(diagms, theta, w_buf, pooled);

    // K3: final rho MLP (latency-pipelined v2)
    rho_kernel<<<BB / K3_ROWS, 256, 0, stream>>>(pooled, r1, rb1, r2, rb2, r3, rb3, out);
}

// Round 7
// 135.943 us; speedup vs baseline: 2.5021x; 1.0699x over previous
//
#include <hip/hip_runtime.h>
#include <hip/hip_bf16.h>
#include <math.h>

// Problem constants (match reference)
#define TT 7
#define BB 512
#define PP 200
#define QQ 64
#define WWH 64
#define WF 256
#define CC 10
#define NN (BB * PP)          // 102400
#define TQ (TT * QQ)          // 448

typedef __attribute__((ext_vector_type(8))) short short8;
typedef __attribute__((ext_vector_type(4))) float f32x4;

static __device__ __forceinline__ unsigned short f2bf(float f) {
    __hip_bfloat16 b = __float2bfloat16(f);   // RNE
    return *reinterpret_cast<unsigned short*>(&b);
}

#define NEG50_OVER_LN2 (-72.13475204444817f)

// ---------------------------------------------------------------------------
// Fused K1+K2: per-point weight MLP (MFMA) + gaussian rep + segment mean-pool.
// One block per (t,b) segment: 3584 blocks x 256 threads (4 waves).
// Phase A: layer 1 (2->64) on VALU; px/py saved to LDS; H bf16 in LDS
//          (XOR-swizzled 16B slots). Rows 200..255 are padding (masked later;
//          global index clamped so the last segment never reads OOB).
// Phase B: layer 2 (64->64) via mfma_f32_16x16x32_bf16 (4 Mtiles x 4 Ntiles
//          x 2 Ksteps per wave); epilogue (+b2, relu, dot w3, +b3, sigmoid)
//          writes w into LDS wv[] (no HBM round-trip).
// Phase C: rep = w * exp(-50*d2) summed over the segment's 200 points,
//          64 q x 4 point-groups, written in topo layout [B, T*Q].
// LDS: H 32KB + W2T 8KB + px/py/wv 3KB + part 1KB ~ 44KB -> 3 blocks/CU,
//      12 waves/CU resident.
// ---------------------------------------------------------------------------
__global__ __launch_bounds__(256, 3) void fused_weight_pool_kernel(
    const float* __restrict__ diagms,   // [T*N, 2]
    const float* __restrict__ theta,    // [Q,2]
    const float* __restrict__ w1,       // [2,64]
    const float* __restrict__ b1,       // [64]
    const float* __restrict__ w2,       // [64,64]
    const float* __restrict__ b2,       // [64]
    const float* __restrict__ w3,       // [64]
    const float* __restrict__ b3,       // [1]
    float* __restrict__ pooled)         // [B, T*Q]
{
    __shared__ unsigned short Hl[256 * 64];    // [point][k] bf16, swizzled
    __shared__ unsigned short W2T[64 * 64];    // [n][k]     bf16, swizzled
    __shared__ float px[256];
    __shared__ float py[256];
    __shared__ float wv[256];
    __shared__ float part[4][QQ];

    const int bid  = blockIdx.x;        // t*BB + b
    const int t    = bid >> 9;          // / 512
    const int b    = bid & (BB - 1);    // % 512
    const int tid  = threadIdx.x;
    const int lane = tid & 63;
    const int wvx  = tid >> 6;

    // ---- stage W2T = w2^T as bf16, swizzled -------------------------------
    {
        const int n  = tid & 63;
        const int j0 = (tid >> 6) * 16;
#pragma unroll
        for (int jj = 0; jj < 16; ++jj) {
            const int j = j0 + jj;
            const float v = w2[j * WWH + n];
            const int off = n * 64 + ((((j >> 3) ^ (n & 7))) << 3) + (j & 7);
            W2T[off] = f2bf(v);
        }
    }

    // ---- phase A: layer 1 + px/py save ------------------------------------
    {
        const int base = t * NN + b * PP;
        int gidx = base + tid;
        if (gidx > TT * NN - 1) gidx = TT * NN - 1;   // clamp (last segment pad)
        const float2 d = reinterpret_cast<const float2*>(diagms)[gidx];
        const float x = d.x, y = d.y;
        px[tid] = x;
        py[tid] = y;
        uint4* Hrow = reinterpret_cast<uint4*>(Hl);
#pragma unroll
        for (int i = 0; i < 8; ++i) {          // 8 groups of 8 k
            unsigned int pk[4];
#pragma unroll
            for (int e = 0; e < 4; ++e) {
                const int j = i * 8 + 2 * e;
                const float h0 = fmaxf(fmaf(x, w1[j],     fmaf(y, w1[WWH + j],     b1[j])),     0.0f);
                const float h1 = fmaxf(fmaf(x, w1[j + 1], fmaf(y, w1[WWH + j + 1], b1[j + 1])), 0.0f);
                pk[e] = (unsigned int)f2bf(h0) | ((unsigned int)f2bf(h1) << 16);
            }
            uint4 v; v.x = pk[0]; v.y = pk[1]; v.z = pk[2]; v.w = pk[3];
            Hrow[tid * 8 + (i ^ (tid & 7))] = v;   // swizzled 16B slot
        }
    }

    __syncthreads();   // W2T + H + px/py visible

    // ---- phase B: MFMA layer 2 + fused epilogue -> wv[] -------------------
    {
        float b2v[4], w3v[4];
#pragma unroll
        for (int nt = 0; nt < 4; ++nt) {
            b2v[nt] = b2[nt * 16 + (lane & 15)];
            w3v[nt] = w3[nt * 16 + (lane & 15)];
        }
        const float b3s = b3[0];

        short8 bfr[2][4];
#pragma unroll
        for (int s = 0; s < 2; ++s) {
#pragma unroll
            for (int nt = 0; nt < 4; ++nt) {
                const int n = nt * 16 + (lane & 15);
                const int slot = ((lane >> 4) + s * 4) ^ (lane & 7);
                bfr[s][nt] = reinterpret_cast<const short8*>(W2T)[n * 8 + slot];
            }
        }

        const int wave_p0 = wvx * 64;

#pragma unroll 1
        for (int m = 0; m < 4; ++m) {
            f32x4 acc[4];
#pragma unroll
            for (int nt = 0; nt < 4; ++nt) acc[nt] = (f32x4){0.f, 0.f, 0.f, 0.f};

#pragma unroll
            for (int s = 0; s < 2; ++s) {
                const int p = wave_p0 + m * 16 + (lane & 15);
                const int slot = ((lane >> 4) + s * 4) ^ (lane & 7);
                const short8 af = reinterpret_cast<const short8*>(Hl)[p * 8 + slot];
#pragma unroll
                for (int nt = 0; nt < 4; ++nt) {
                    acc[nt] = __builtin_amdgcn_mfma_f32_16x16x32_bf16(af, bfr[s][nt], acc[nt], 0, 0, 0);
                }
            }

            float sum0 = 0.f, sum1 = 0.f, sum2 = 0.f, sum3 = 0.f;
#pragma unroll
            for (int nt = 0; nt < 4; ++nt) {
                sum0 = fmaf(fmaxf(acc[nt][0] + b2v[nt], 0.f), w3v[nt], sum0);
                sum1 = fmaf(fmaxf(acc[nt][1] + b2v[nt], 0.f), w3v[nt], sum1);
                sum2 = fmaf(fmaxf(acc[nt][2] + b2v[nt], 0.f), w3v[nt], sum2);
                sum3 = fmaf(fmaxf(acc[nt][3] + b2v[nt], 0.f), w3v[nt], sum3);
            }
#pragma unroll
            for (int off = 1; off < 16; off <<= 1) {
                sum0 += __shfl_xor(sum0, off, 64);
                sum1 += __shfl_xor(sum1, off, 64);
                sum2 += __shfl_xor(sum2, off, 64);
                sum3 += __shfl_xor(sum3, off, 64);
            }
            const int r_sel = lane & 15;
            if (r_sel < 4) {
                const float sv = (r_sel == 0) ? sum0 : (r_sel == 1) ? sum1
                               : (r_sel == 2) ? sum2 : sum3;   // static select
                const float wa = sv + b3s;
                const int prow = wave_p0 + m * 16 + ((lane >> 4) << 2) + r_sel;
                wv[prow] = 1.0f / (1.0f + __expf(-wa));
            }
        }
    }

    __syncthreads();   // wv visible

    // ---- phase C: gaussian rep * w, mean-pool over 200 points -------------
    {
        const int q = tid & (QQ - 1);
        const int g = tid >> 6;             // 0..3, uniform per wave
        const float2 th = reinterpret_cast<const float2*>(theta)[q];
        const float tx = th.x;
        const float ty = th.y;

        float acc = 0.0f;
        const int p0 = g * (PP / 4);
#pragma unroll 5
        for (int p = p0; p < p0 + PP / 4; ++p) {
            const float dx = px[p] - tx;
            const float dy = py[p] - ty;
            acc = fmaf(wv[p], exp2f(fmaf(dx, dx, dy * dy) * NEG50_OVER_LN2), acc);
        }
        part[g][q] = acc;
    }
    __syncthreads();

    if (tid < QQ) {
        const float s = (part[0][tid] + part[1][tid]) + (part[2][tid] + part[3][tid]);
        pooled[b * TQ + t * QQ + tid] = s * (1.0f / (float)PP);
    }
}

// ---------------------------------------------------------------------------
// Kernel 3 (v3): rho MLP, latency-pipelined + TLP.
// Round-6 diagnosis: pipeline was fine but 1 wave/SIMD => ~900cy HBM
// first-touch misses fully exposed (704 loads / 8-deep * 900cy ~= 33us).
// Fix: 1024 threads/block (16 waves => 4 waves/SIMD), reduction split 4-ways
// (g in 0..3), partials combined in LDS. Per-thread loads 704 -> 176, and
// 4 waves/SIMD overlap the misses.
// ---------------------------------------------------------------------------
#define K3_ROWS 2
__global__ __launch_bounds__(1024, 4) void rho_kernel(
    const float* __restrict__ pooled,   // [B, T*Q]
    const float* __restrict__ r1,       // [448,256]
    const float* __restrict__ rb1,      // [256]
    const float* __restrict__ r2,       // [256,256]
    const float* __restrict__ rb2,      // [256]
    const float* __restrict__ r3,       // [256,10]
    const float* __restrict__ rb3,      // [10]
    float* __restrict__ out)            // [B, C]
{
    const int b0  = blockIdx.x * K3_ROWS;
    const int tid = threadIdx.x;        // 0..1023
    const int k   = tid & (WF - 1);     // feature 0..255
    const int g   = tid >> 8;           // reduction group 0..3

    __shared__ float tp[K3_ROWS * TQ];  // 896 floats
    __shared__ float z1[K3_ROWS][WF];
    __shared__ float z2[K3_ROWS][WF];
    __shared__ float part[4][K3_ROWS][WF];
    __shared__ float red[8][CC];

    // ---- stage the 2 topo rows (coalesced) --------------------------------
    if (tid < K3_ROWS * TQ) tp[tid] = pooled[(size_t)b0 * TQ + tid];
    __syncthreads();

    // ---- layer 1: 448-deep, split 4x112, 8-wide double-buffered -----------
    {
        float acc0 = 0.0f, acc1 = 0.0f;
        const float* r1c = r1 + k;
        const int ibase = g * (TQ / 4);              // 112 per group
        float rv0[8], rv1[8];
#pragma unroll
        for (int e = 0; e < 8; ++e) rv0[e] = r1c[(ibase + e) * WF];
#pragma unroll 1
        for (int i0 = ibase; i0 < ibase + TQ / 4; i0 += 16) {
#pragma unroll
            for (int e = 0; e < 8; ++e) rv1[e] = r1c[(i0 + 8 + e) * WF];
#pragma unroll
            for (int e = 0; e < 8; ++e) {
                acc0 = fmaf(tp[i0 + e],      rv0[e], acc0);
                acc1 = fmaf(tp[TQ + i0 + e], rv0[e], acc1);
            }
            if (i0 + 16 < ibase + TQ / 4) {
#pragma unroll
                for (int e = 0; e < 8; ++e) rv0[e] = r1c[(i0 + 16 + e) * WF];
            }
#pragma unroll
            for (int e = 0; e < 8; ++e) {
                acc0 = fmaf(tp[i0 + 8 + e],      rv1[e], acc0);
                acc1 = fmaf(tp[TQ + i0 + 8 + e], rv1[e], acc1);
            }
        }
        part[g][0][k] = acc0;
        part[g][1][k] = acc1;
    }
    __syncthreads();
    if (tid < 2 * WF) {
        const int r = tid >> 8;         // row 0/1
        const int kk = tid & (WF - 1);
        z1[r][kk] = fmaxf(part[0][r][kk] + part[1][r][kk] +
                          part[2][r][kk] + part[3][r][kk] + rb1[kk], 0.0f);
    }
    __syncthreads();

    // ---- layer 2: 256-deep, split 4x64 ------------------------------------
    {
        float acc0 = 0.0f, acc1 = 0.0f;
        const float* r2c = r2 + k;
        const int ibase = g * (WF / 4);              // 64 per group
        float rv0[8], rv1[8];
#pragma unroll
        for (int e = 0; e < 8; ++e) rv0[e] = r2c[(ibase + e) * WF];
#pragma unroll 1
        for (int i0 = ibase; i0 < ibase + WF / 4; i0 += 16) {
#pragma unroll
            for (int e = 0; e < 8; ++e) rv1[e] = r2c[(i0 + 8 + e) * WF];
#pragma unroll
            for (int e = 0; e < 8; ++e) {
                acc0 = fmaf(z1[0][i0 + e], rv0[e], acc0);
                acc1 = fmaf(z1[1][i0 + e], rv0[e], acc1);
            }
            if (i0 + 16 < ibase + WF / 4) {
#pragma unroll
                for (int e = 0; e < 8; ++e) rv0[e] = r2c[(i0 + 16 + e) * WF];
            }
#pragma unroll
            for (int e = 0; e < 8; ++e) {
                acc0 = fmaf(z1[0][i0 + 8 + e], rv1[e], acc0);
                acc1 = fmaf(z1[1][i0 + 8 + e], rv1[e], acc1);
            }
        }
        part[g][0][k] = acc0;
        part[g][1][k] = acc1;
    }
    __syncthreads();
    if (tid < 2 * WF) {
        const int r = tid >> 8;
        const int kk = tid & (WF - 1);
        z2[r][kk] = fmaxf(part[0][r][kk] + part[1][r][kk] +
                          part[2][r][kk] + part[3][r][kk] + rb2[kk], 0.0f);
    }
    __syncthreads();

    // ---- layer 3: outer product + wave reduce (threads 0..511) ------------
    if (tid < 512) {
        const int r    = tid >> 8;      // row 0/1
        const int kk   = tid & (WF - 1);
        const int lane = tid & 63;
        const int wvi  = tid >> 6;      // 0..7
        const float z = z2[r][kk];
        float p[CC];
#pragma unroll
        for (int c = 0; c < CC; ++c) p[c] = z * r3[kk * CC + c];
#pragma unroll
        for (int off = 32; off >= 1; off >>= 1) {
#pragma unroll
            for (int c = 0; c < CC; ++c) p[c] += __shfl_xor(p[c], off, 64);
        }
        if (lane == 0) {
#pragma unroll
            for (int c = 0; c < CC; ++c) red[wvi][c] = p[c];
        }
    }
    __syncthreads();
    if (tid < K3_ROWS * CC) {
        const int r = tid / CC;
        const int c = tid % CC;
        out[(size_t)(b0 + r) * CC + c] =
            red[r * 4 + 0][c] + red[r * 4 + 1][c] +
            red[r * 4 + 2][c] + red[r * 4 + 3][c] + rb3[c];
    }
}

// ---------------------------------------------------------------------------
extern "C" void kernel_launch(void* const* d_in, const int* in_sizes, int n_in,
                              void* d_out, int out_size, void* d_ws, size_t ws_size,
                              hipStream_t stream)
{
    const float* diagms = (const float*)d_in[0];
    // d_in[1] = seg_ids (int32) — structurally n/P with equal counts; unused.
    const float* theta  = (const float*)d_in[2];
    const float* w1     = (const float*)d_in[3];
    const float* b1     = (const float*)d_in[4];
    const float* w2     = (const float*)d_in[5];
    const float* b2     = (const float*)d_in[6];
    const float* w3     = (const float*)d_in[7];
    const float* b3     = (const float*)d_in[8];
    const float* r1     = (const float*)d_in[9];
    const float* rb1    = (const float*)d_in[10];
    const float* r2     = (const float*)d_in[11];
    const float* rb2    = (const float*)d_in[12];
    const float* r3     = (const float*)d_in[13];
    const float* rb3    = (const float*)d_in[14];
    float* out = (float*)d_out;

    float* pooled = (float*)d_ws;            // [B, T*Q]

    // Fused K1+K2: one block per (t,b) segment
    fused_weight_pool_kernel<<<TT * BB, 256, 0, stream>>>(
        diagms, theta, w1, b1, w2, b2, w3, b3, pooled);

    // K3: final rho MLP (TLP-pipelined v3)
    rho_kernel<<<BB / K3_ROWS, 1024, 0, stream>>>(
        pooled, r1, rb1, r2, rb2, r3, rb3, out);
}

// Round 9
// 127.914 us; speedup vs baseline: 2.6591x; 1.0628x over previous
//
#include <hip/hip_runtime.h>
#include <hip/hip_bf16.h>
#include <math.h>

// Problem constants (match reference)
#define TT 7
#define BB 512
#define PP 200
#define QQ 64
#define WWH 64
#define WF 256
#define CC 10
#define NN (BB * PP)          // 102400
#define TQ (TT * QQ)          // 448

typedef __attribute__((ext_vector_type(8))) short short8;
typedef __attribute__((ext_vector_type(4))) float f32x4;

static __device__ __forceinline__ unsigned short f2bf(float f) {
    __hip_bfloat16 b = __float2bfloat16(f);   // RNE
    return *reinterpret_cast<unsigned short*>(&b);
}

#define NEG50_OVER_LN2 (-72.13475204444817f)

// ---------------------------------------------------------------------------
// Kernel 1 (MFMA): per-point weight MLP. (round-5 version, verified)
// 256 points/block, 2800 blocks (no padding waste), 4 waves x 64 points.
// ---------------------------------------------------------------------------
__global__ __launch_bounds__(256, 4) void point_weight_kernel(
    const float* __restrict__ diagms,   // [T*N, 2]
    const float* __restrict__ w1,       // [2,64]
    const float* __restrict__ b1,       // [64]
    const float* __restrict__ w2,       // [64,64]
    const float* __restrict__ b2,       // [64]
    const float* __restrict__ w3,       // [64]
    const float* __restrict__ b3,       // [1]
    float* __restrict__ w_out)          // [T*N]
{
    __shared__ unsigned short Hl[256 * 64];    // [point][k] bf16, swizzled
    __shared__ unsigned short W2T[64 * 64];    // [n][k]     bf16, swizzled

    const int tid  = threadIdx.x;
    const int lane = tid & 63;
    const int wv   = tid >> 6;

    // ---- stage W2T = w2^T as bf16, swizzled -------------------------------
    {
        const int n  = tid & 63;
        const int j0 = (tid >> 6) * 16;
#pragma unroll
        for (int jj = 0; jj < 16; ++jj) {
            const int j = j0 + jj;
            const float v = w2[j * WWH + n];
            const int off = n * 64 + ((((j >> 3) ^ (n & 7))) << 3) + (j & 7);
            W2T[off] = f2bf(v);
        }
    }

    // ---- layer 1: h = relu(x*W1[0,:] + y*W1[1,:] + b1) -> Hl row (bf16) ----
    {
        const int p = tid;  // block-local point
        const float2 d = reinterpret_cast<const float2*>(diagms)[(size_t)blockIdx.x * 256 + p];
        const float x = d.x, y = d.y;
        uint4* Hrow = reinterpret_cast<uint4*>(Hl);
#pragma unroll
        for (int i = 0; i < 8; ++i) {          // 8 groups of 8 k
            unsigned int pk[4];
#pragma unroll
            for (int e = 0; e < 4; ++e) {
                const int j = i * 8 + 2 * e;
                const float h0 = fmaxf(fmaf(x, w1[j],     fmaf(y, w1[WWH + j],     b1[j])),     0.0f);
                const float h1 = fmaxf(fmaf(x, w1[j + 1], fmaf(y, w1[WWH + j + 1], b1[j + 1])), 0.0f);
                pk[e] = (unsigned int)f2bf(h0) | ((unsigned int)f2bf(h1) << 16);
            }
            uint4 v; v.x = pk[0]; v.y = pk[1]; v.z = pk[2]; v.w = pk[3];
            Hrow[p * 8 + (i ^ (p & 7))] = v;   // swizzled 16B slot
        }
    }

    __syncthreads();   // W2T + H visible to all

    // ---- per-lane constants for epilogue ----------------------------------
    float b2v[4], w3v[4];
#pragma unroll
    for (int nt = 0; nt < 4; ++nt) {
        b2v[nt] = b2[nt * 16 + (lane & 15)];
        w3v[nt] = w3[nt * 16 + (lane & 15)];
    }
    const float b3s = b3[0];

    // ---- B fragments: 2 ksteps x 4 ntiles, reused across all Mtiles -------
    short8 bf[2][4];
#pragma unroll
    for (int s = 0; s < 2; ++s) {
#pragma unroll
        for (int nt = 0; nt < 4; ++nt) {
            const int n = nt * 16 + (lane & 15);
            const int slot = ((lane >> 4) + s * 4) ^ (lane & 7);
            bf[s][nt] = reinterpret_cast<const short8*>(W2T)[n * 8 + slot];
        }
    }

    const int wave_p0 = wv * 64;
    const size_t out_base = (size_t)blockIdx.x * 256;

#pragma unroll 1
    for (int m = 0; m < 4; ++m) {
        f32x4 acc[4];
#pragma unroll
        for (int nt = 0; nt < 4; ++nt) acc[nt] = (f32x4){0.f, 0.f, 0.f, 0.f};

#pragma unroll
        for (int s = 0; s < 2; ++s) {
            const int p = wave_p0 + m * 16 + (lane & 15);
            const int slot = ((lane >> 4) + s * 4) ^ (lane & 7);
            const short8 af = reinterpret_cast<const short8*>(Hl)[p * 8 + slot];
#pragma unroll
            for (int nt = 0; nt < 4; ++nt) {
                acc[nt] = __builtin_amdgcn_mfma_f32_16x16x32_bf16(af, bf[s][nt], acc[nt], 0, 0, 0);
            }
        }

        // ---- epilogue: +b2, relu, dot w3, 16-lane reduce, sigmoid ---------
        float sum0 = 0.f, sum1 = 0.f, sum2 = 0.f, sum3 = 0.f;
#pragma unroll
        for (int nt = 0; nt < 4; ++nt) {
            sum0 = fmaf(fmaxf(acc[nt][0] + b2v[nt], 0.f), w3v[nt], sum0);
            sum1 = fmaf(fmaxf(acc[nt][1] + b2v[nt], 0.f), w3v[nt], sum1);
            sum2 = fmaf(fmaxf(acc[nt][2] + b2v[nt], 0.f), w3v[nt], sum2);
            sum3 = fmaf(fmaxf(acc[nt][3] + b2v[nt], 0.f), w3v[nt], sum3);
        }
#pragma unroll
        for (int off = 1; off < 16; off <<= 1) {
            sum0 += __shfl_xor(sum0, off, 64);
            sum1 += __shfl_xor(sum1, off, 64);
            sum2 += __shfl_xor(sum2, off, 64);
            sum3 += __shfl_xor(sum3, off, 64);
        }
        const int r_sel = lane & 15;
        if (r_sel < 4) {
            const float sv = (r_sel == 0) ? sum0 : (r_sel == 1) ? sum1
                           : (r_sel == 2) ? sum2 : sum3;           // static select
            const float wa = sv + b3s;
            const float wsig = 1.0f / (1.0f + __expf(-wa));
            const int prow = wave_p0 + m * 16 + ((lane >> 4) << 2) + r_sel;
            w_out[out_base + prow] = wsig;
        }
    }
}

// ---------------------------------------------------------------------------
// Kernel 2 (v2): gaussian rep * weight, mean-pool per segment.
// One block per (t,b) segment of P=200 points. 256 thr = 64 q x 4 groups.
// (x,y,w) packed into ONE float4 LDS array -> inner loop does 1 broadcast
// ds_read_b128 per point instead of 3 ds_read_b32.
// ---------------------------------------------------------------------------
__global__ __launch_bounds__(256) void rep_pool_kernel(
    const float* __restrict__ diagms,   // [T*N, 2]
    const float* __restrict__ theta,    // [Q,2]
    const float* __restrict__ w_in,     // [T*N]
    float* __restrict__ pooled)         // [B, T*Q]
{
    const int bid = blockIdx.x;         // t*B + b
    const int t = bid >> 9;             // / 512
    const int b = bid & (BB - 1);       // % 512
    const int tid = threadIdx.x;

    __shared__ float4 pxyw[PP];

    if (tid < PP) {
        const int n = t * NN + b * PP + tid;
        const float2 d = reinterpret_cast<const float2*>(diagms)[n];
        float4 v;
        v.x = d.x;
        v.y = d.y;
        v.z = w_in[n];
        v.w = 0.0f;
        pxyw[tid] = v;
    }
    __syncthreads();

    const int q = tid & (QQ - 1);
    const int g = tid >> 6;             // 0..3, uniform per wave
    const float2 th = reinterpret_cast<const float2*>(theta)[q];
    const float tx = th.x;
    const float ty = th.y;

    float acc = 0.0f;
    const int p0 = g * (PP / 4);
#pragma unroll 5
    for (int p = p0; p < p0 + PP / 4; ++p) {
        const float4 v = pxyw[p];       // broadcast ds_read_b128
        const float dx = v.x - tx;
        const float dy = v.y - ty;
        acc = fmaf(v.z, exp2f(fmaf(dx, dx, dy * dy) * NEG50_OVER_LN2), acc);
    }

    __shared__ float part[4][QQ];
    part[g][q] = acc;
    __syncthreads();

    if (tid < QQ) {
        const float s = (part[0][tid] + part[1][tid]) + (part[2][tid] + part[3][tid]);
        pooled[b * TQ + t * QQ + tid] = s * (1.0f / (float)PP);
    }
}

// ---------------------------------------------------------------------------
// Kernel 3 (v3): rho MLP, latency-pipelined + TLP. (round-6 version, ~9us)
// ---------------------------------------------------------------------------
#define K3_ROWS 2
__global__ __launch_bounds__(1024, 4) void rho_kernel(
    const float* __restrict__ pooled,   // [B, T*Q]
    const float* __restrict__ r1,       // [448,256]
    const float* __restrict__ rb1,      // [256]
    const float* __restrict__ r2,       // [256,256]
    const float* __restrict__ rb2,      // [256]
    const float* __restrict__ r3,       // [256,10]
    const float* __restrict__ rb3,      // [10]
    float* __restrict__ out)            // [B, C]
{
    const int b0  = blockIdx.x * K3_ROWS;
    const int tid = threadIdx.x;        // 0..1023
    const int k   = tid & (WF - 1);     // feature 0..255
    const int g   = tid >> 8;           // reduction group 0..3

    __shared__ float tp[K3_ROWS * TQ];  // 896 floats
    __shared__ float z1[K3_ROWS][WF];
    __shared__ float z2[K3_ROWS][WF];
    __shared__ float part[4][K3_ROWS][WF];
    __shared__ float red[8][CC];

    // ---- stage the 2 topo rows (coalesced) --------------------------------
    if (tid < K3_ROWS * TQ) tp[tid] = pooled[(size_t)b0 * TQ + tid];
    __syncthreads();

    // ---- layer 1: 448-deep, split 4x112, 8-wide double-buffered -----------
    {
        float acc0 = 0.0f, acc1 = 0.0f;
        const float* r1c = r1 + k;
        const int ibase = g * (TQ / 4);              // 112 per group
        float rv0[8], rv1[8];
#pragma unroll
        for (int e = 0; e < 8; ++e) rv0[e] = r1c[(ibase + e) * WF];
#pragma unroll 1
        for (int i0 = ibase; i0 < ibase + TQ / 4; i0 += 16) {
#pragma unroll
            for (int e = 0; e < 8; ++e) rv1[e] = r1c[(i0 + 8 + e) * WF];
#pragma unroll
            for (int e = 0; e < 8; ++e) {
                acc0 = fmaf(tp[i0 + e],      rv0[e], acc0);
                acc1 = fmaf(tp[TQ + i0 + e], rv0[e], acc1);
            }
            if (i0 + 16 < ibase + TQ / 4) {
#pragma unroll
                for (int e = 0; e < 8; ++e) rv0[e] = r1c[(i0 + 16 + e) * WF];
            }
#pragma unroll
            for (int e = 0; e < 8; ++e) {
                acc0 = fmaf(tp[i0 + 8 + e],      rv1[e], acc0);
                acc1 = fmaf(tp[TQ + i0 + 8 + e], rv1[e], acc1);
            }
        }
        part[g][0][k] = acc0;
        part[g][1][k] = acc1;
    }
    __syncthreads();
    if (tid < 2 * WF) {
        const int r = tid >> 8;         // row 0/1
        const int kk = tid & (WF - 1);
        z1[r][kk] = fmaxf(part[0][r][kk] + part[1][r][kk] +
                          part[2][r][kk] + part[3][r][kk] + rb1[kk], 0.0f);
    }
    __syncthreads();

    // ---- layer 2: 256-deep, split 4x64 ------------------------------------
    {
        float acc0 = 0.0f, acc1 = 0.0f;
        const float* r2c = r2 + k;
        const int ibase = g * (WF / 4);              // 64 per group
        float rv0[8], rv1[8];
#pragma unroll
        for (int e = 0; e < 8; ++e) rv0[e] = r2c[(ibase + e) * WF];
#pragma unroll 1
        for (int i0 = ibase; i0 < ibase + WF / 4; i0 += 16) {
#pragma unroll
            for (int e = 0; e < 8; ++e) rv1[e] = r2c[(i0 + 8 + e) * WF];
#pragma unroll
            for (int e = 0; e < 8; ++e) {
                acc0 = fmaf(z1[0][i0 + e], rv0[e], acc0);
                acc1 = fmaf(z1[1][i0 + e], rv0[e], acc1);
            }
            if (i0 + 16 < ibase + WF / 4) {
#pragma unroll
                for (int e = 0; e < 8; ++e) rv0[e] = r2c[(i0 + 16 + e) * WF];
            }
#pragma unroll
            for (int e = 0; e < 8; ++e) {
                acc0 = fmaf(z1[0][i0 + 8 + e], rv1[e], acc0);
                acc1 = fmaf(z1[1][i0 + 8 + e], rv1[e], acc1);
            }
        }
        part[g][0][k] = acc0;
        part[g][1][k] = acc1;
    }
    __syncthreads();
    if (tid < 2 * WF) {
        const int r = tid >> 8;
        const int kk = tid & (WF - 1);
        z2[r][kk] = fmaxf(part[0][r][kk] + part[1][r][kk] +
                          part[2][r][kk] + part[3][r][kk] + rb2[kk], 0.0f);
    }
    __syncthreads();

    // ---- layer 3: outer product + wave reduce (threads 0..511) ------------
    if (tid < 512) {
        const int r    = tid >> 8;      // row 0/1
        const int kk   = tid & (WF - 1);
        const int lane = tid & 63;
        const int wvi  = tid >> 6;      // 0..7
        const float z = z2[r][kk];
        float p[CC];
#pragma unroll
        for (int c = 0; c < CC; ++c) p[c] = z * r3[kk * CC + c];
#pragma unroll
        for (int off = 32; off >= 1; off >>= 1) {
#pragma unroll
            for (int c = 0; c < CC; ++c) p[c] += __shfl_xor(p[c], off, 64);
        }
        if (lane == 0) {
#pragma unroll
            for (int c = 0; c < CC; ++c) red[wvi][c] = p[c];
        }
    }
    __syncthreads();
    if (tid < K3_ROWS * CC) {
        const int r = tid / CC;
        const int c = tid % CC;
        out[(size_t)(b0 + r) * CC + c] =
            red[r * 4 + 0][c] + red[r * 4 + 1][c] +
            red[r * 4 + 2][c] + red[r * 4 + 3][c] + rb3[c];
    }
}

// ---------------------------------------------------------------------------
extern "C" void kernel_launch(void* const* d_in, const int* in_sizes, int n_in,
                              void* d_out, int out_size, void* d_ws, size_t ws_size,
                              hipStream_t stream)
{
    const float* diagms = (const float*)d_in[0];
    // d_in[1] = seg_ids (int32) — structurally n/P with equal counts; unused.
    const float* theta  = (const float*)d_in[2];
    const float* w1     = (const float*)d_in[3];
    const float* b1     = (const float*)d_in[4];
    const float* w2     = (const float*)d_in[5];
    const float* b2     = (const float*)d_in[6];
    const float* w3     = (const float*)d_in[7];
    const float* b3     = (const float*)d_in[8];
    const float* r1     = (const float*)d_in[9];
    const float* rb1    = (const float*)d_in[10];
    const float* r2     = (const float*)d_in[11];
    const float* rb2    = (const float*)d_in[12];
    const float* r3     = (const float*)d_in[13];
    const float* rb3    = (const float*)d_in[14];
    float* out = (float*)d_out;

    float* w_buf  = (float*)d_ws;            // [T*N]
    float* pooled = w_buf + (size_t)TT * NN; // [B, T*Q]

    const int total = TT * NN;               // 716800

    // K1: per-point weight MLP (MFMA) — 2800 blocks x 256 points
    point_weight_kernel<<<total / 256, 256, 0, stream>>>(
        diagms, w1, b1, w2, b2, w3, b3, w_buf);

    // K2: gaussian rep + segment mean-pool (float4-packed LDS)
    rep_pool_kernel<<<TT * BB, 256, 0, stream>>>(diagms, theta, w_buf, pooled);

    // K3: final rho MLP (TLP-pipelined v3)
    rho_kernel<<<BB / K3_ROWS, 1024, 0, stream>>>(
        pooled, r1, rb1, r2, rb2, r3, rb3, out);
}

// Round 10
// 125.619 us; speedup vs baseline: 2.7077x; 1.0183x over previous
//
#include <hip/hip_runtime.h>
#include <hip/hip_bf16.h>
#include <math.h>

// Problem constants (match reference)
#define TT 7
#define BB 512
#define PP 200
#define QQ 64
#define WWH 64
#define WF 256
#define CC 10
#define NN (BB * PP)          // 102400
#define TQ (TT * QQ)          // 448

typedef __attribute__((ext_vector_type(8))) short short8;
typedef __attribute__((ext_vector_type(4))) float f32x4;

static __device__ __forceinline__ unsigned short f2bf(float f) {
    __hip_bfloat16 b = __float2bfloat16(f);   // RNE
    return *reinterpret_cast<unsigned short*>(&b);
}

// Full 16-lane-row sum via rotate-DPP (row_ror:8/4/2/1). Result valid in ALL
// lanes of each 16-lane DPP row. VALU-pipe only (no ds_swizzle / LDS pipe).
static __device__ __forceinline__ float dpp_row_reduce16(float v) {
    int x;
    x = __builtin_amdgcn_update_dpp(0, __float_as_int(v), 0x128, 0xf, 0xf, false); // ror:8
    v += __int_as_float(x);
    x = __builtin_amdgcn_update_dpp(0, __float_as_int(v), 0x124, 0xf, 0xf, false); // ror:4
    v += __int_as_float(x);
    x = __builtin_amdgcn_update_dpp(0, __float_as_int(v), 0x122, 0xf, 0xf, false); // ror:2
    v += __int_as_float(x);
    x = __builtin_amdgcn_update_dpp(0, __float_as_int(v), 0x121, 0xf, 0xf, false); // ror:1
    v += __int_as_float(x);
    return v;
}

#define NEG50_OVER_LN2 (-72.13475204444817f)

// ---------------------------------------------------------------------------
// Kernel 1 (MFMA, v2): per-point weight MLP.
// 256 points/block, 2800 blocks, 4 waves x 64 points.
// v2 changes vs round-5 version (theory: K1 ~25-30us, 3-4x over floor):
//  (1) lgkm hygiene: layer-1 computes ALL 64 h into 32 packed VGPRs first
//      (pure s_load + VALU region), then issues the 8 ds_write_b128 together
//      -> no mixed s_load/ds lgkmcnt(0) drains inside the unrolled loop.
//  (2) epilogue reduce on VALU pipe via rotate-DPP (dpp_row_reduce16) instead
//      of 64 __shfl_xor (ds_swizzle, LDS pipe + lgkm waits).
// ---------------------------------------------------------------------------
__global__ __launch_bounds__(256, 4) void point_weight_kernel(
    const float* __restrict__ diagms,   // [T*N, 2]
    const float* __restrict__ w1,       // [2,64]
    const float* __restrict__ b1,       // [64]
    const float* __restrict__ w2,       // [64,64]
    const float* __restrict__ b2,       // [64]
    const float* __restrict__ w3,       // [64]
    const float* __restrict__ b3,       // [1]
    float* __restrict__ w_out)          // [T*N]
{
    __shared__ unsigned short Hl[256 * 64];    // [point][k] bf16, swizzled
    __shared__ unsigned short W2T[64 * 64];    // [n][k]     bf16, swizzled

    const int tid  = threadIdx.x;
    const int lane = tid & 63;
    const int wv   = tid >> 6;

    // ---- layer 1 compute: h[64] -> 32 packed bf16x2 VGPRs (NO ds ops) -----
    unsigned int hp[32];
    {
        const float2 d = reinterpret_cast<const float2*>(diagms)[(size_t)blockIdx.x * 256 + tid];
        const float x = d.x, y = d.y;
#pragma unroll
        for (int j2 = 0; j2 < 32; ++j2) {
            const int j = 2 * j2;
            const float h0 = fmaxf(fmaf(x, w1[j],     fmaf(y, w1[WWH + j],     b1[j])),     0.0f);
            const float h1 = fmaxf(fmaf(x, w1[j + 1], fmaf(y, w1[WWH + j + 1], b1[j + 1])), 0.0f);
            hp[j2] = (unsigned int)f2bf(h0) | ((unsigned int)f2bf(h1) << 16);
        }
    }

    // ---- stage W2T = w2^T as bf16, swizzled (global->VALU->ds, vmcnt-only) -
    {
        const int n  = tid & 63;
        const int j0 = (tid >> 6) * 16;
#pragma unroll
        for (int jj = 0; jj < 16; ++jj) {
            const int j = j0 + jj;
            const float v = w2[j * WWH + n];
            const int off = n * 64 + ((((j >> 3) ^ (n & 7))) << 3) + (j & 7);
            W2T[off] = f2bf(v);
        }
    }

    // ---- layer 1 write: 8 x ds_write_b128, issued together ----------------
    {
        uint4* Hrow = reinterpret_cast<uint4*>(Hl);
#pragma unroll
        for (int i = 0; i < 8; ++i) {
            uint4 v;
            v.x = hp[4 * i + 0];
            v.y = hp[4 * i + 1];
            v.z = hp[4 * i + 2];
            v.w = hp[4 * i + 3];
            Hrow[tid * 8 + (i ^ (tid & 7))] = v;   // swizzled 16B slot
        }
    }

    __syncthreads();   // W2T + H visible to all

    // ---- per-lane constants for epilogue ----------------------------------
    float b2v[4], w3v[4];
#pragma unroll
    for (int nt = 0; nt < 4; ++nt) {
        b2v[nt] = b2[nt * 16 + (lane & 15)];
        w3v[nt] = w3[nt * 16 + (lane & 15)];
    }
    const float b3s = b3[0];

    // ---- B fragments: 2 ksteps x 4 ntiles, reused across all Mtiles -------
    short8 bf[2][4];
#pragma unroll
    for (int s = 0; s < 2; ++s) {
#pragma unroll
        for (int nt = 0; nt < 4; ++nt) {
            const int n = nt * 16 + (lane & 15);
            const int slot = ((lane >> 4) + s * 4) ^ (lane & 7);
            bf[s][nt] = reinterpret_cast<const short8*>(W2T)[n * 8 + slot];
        }
    }

    const int wave_p0 = wv * 64;
    const size_t out_base = (size_t)blockIdx.x * 256;

#pragma unroll 1
    for (int m = 0; m < 4; ++m) {
        f32x4 acc[4];
#pragma unroll
        for (int nt = 0; nt < 4; ++nt) acc[nt] = (f32x4){0.f, 0.f, 0.f, 0.f};

#pragma unroll
        for (int s = 0; s < 2; ++s) {
            const int p = wave_p0 + m * 16 + (lane & 15);
            const int slot = ((lane >> 4) + s * 4) ^ (lane & 7);
            const short8 af = reinterpret_cast<const short8*>(Hl)[p * 8 + slot];
#pragma unroll
            for (int nt = 0; nt < 4; ++nt) {
                acc[nt] = __builtin_amdgcn_mfma_f32_16x16x32_bf16(af, bf[s][nt], acc[nt], 0, 0, 0);
            }
        }

        // ---- epilogue: +b2, relu, dot w3, rotate-DPP 16-lane reduce -------
        float sum0 = 0.f, sum1 = 0.f, sum2 = 0.f, sum3 = 0.f;
#pragma unroll
        for (int nt = 0; nt < 4; ++nt) {
            sum0 = fmaf(fmaxf(acc[nt][0] + b2v[nt], 0.f), w3v[nt], sum0);
            sum1 = fmaf(fmaxf(acc[nt][1] + b2v[nt], 0.f), w3v[nt], sum1);
            sum2 = fmaf(fmaxf(acc[nt][2] + b2v[nt], 0.f), w3v[nt], sum2);
            sum3 = fmaf(fmaxf(acc[nt][3] + b2v[nt], 0.f), w3v[nt], sum3);
        }
        sum0 = dpp_row_reduce16(sum0);
        sum1 = dpp_row_reduce16(sum1);
        sum2 = dpp_row_reduce16(sum2);
        sum3 = dpp_row_reduce16(sum3);

        const int r_sel = lane & 15;
        if (r_sel < 4) {
            const float sv = (r_sel == 0) ? sum0 : (r_sel == 1) ? sum1
                           : (r_sel == 2) ? sum2 : sum3;           // static select
            const float wa = sv + b3s;
            const float wsig = 1.0f / (1.0f + __expf(-wa));
            const int prow = wave_p0 + m * 16 + ((lane >> 4) << 2) + r_sel;
            w_out[out_base + prow] = wsig;
        }
    }
}

// ---------------------------------------------------------------------------
// Kernel 2 (v2): gaussian rep * weight, mean-pool per segment. (unchanged)
// One block per (t,b) segment of P=200 points. 256 thr = 64 q x 4 groups.
// (x,y,w) packed in ONE float4 LDS array -> 1 broadcast ds_read_b128/point.
// ---------------------------------------------------------------------------
__global__ __launch_bounds__(256) void rep_pool_kernel(
    const float* __restrict__ diagms,   // [T*N, 2]
    const float* __restrict__ theta,    // [Q,2]
    const float* __restrict__ w_in,     // [T*N]
    float* __restrict__ pooled)         // [B, T*Q]
{
    const int bid = blockIdx.x;         // t*B + b
    const int t = bid >> 9;             // / 512
    const int b = bid & (BB - 1);       // % 512
    const int tid = threadIdx.x;

    __shared__ float4 pxyw[PP];

    if (tid < PP) {
        const int n = t * NN + b * PP + tid;
        const float2 d = reinterpret_cast<const float2*>(diagms)[n];
        float4 v;
        v.x = d.x;
        v.y = d.y;
        v.z = w_in[n];
        v.w = 0.0f;
        pxyw[tid] = v;
    }
    __syncthreads();

    const int q = tid & (QQ - 1);
    const int g = tid >> 6;             // 0..3, uniform per wave
    const float2 th = reinterpret_cast<const float2*>(theta)[q];
    const float tx = th.x;
    const float ty = th.y;

    float acc = 0.0f;
    const int p0 = g * (PP / 4);
#pragma unroll 5
    for (int p = p0; p < p0 + PP / 4; ++p) {
        const float4 v = pxyw[p];       // broadcast ds_read_b128
        const float dx = v.x - tx;
        const float dy = v.y - ty;
        acc = fmaf(v.z, exp2f(fmaf(dx, dx, dy * dy) * NEG50_OVER_LN2), acc);
    }

    __shared__ float part[4][QQ];
    part[g][q] = acc;
    __syncthreads();

    if (tid < QQ) {
        const float s = (part[0][tid] + part[1][tid]) + (part[2][tid] + part[3][tid]);
        pooled[b * TQ + t * QQ + tid] = s * (1.0f / (float)PP);
    }
}

// ---------------------------------------------------------------------------
// Kernel 3 (v3): rho MLP, latency-pipelined + TLP. (unchanged, ~9us)
// ---------------------------------------------------------------------------
#define K3_ROWS 2
__global__ __launch_bounds__(1024, 4) void rho_kernel(
    const float* __restrict__ pooled,   // [B, T*Q]
    const float* __restrict__ r1,       // [448,256]
    const float* __restrict__ rb1,      // [256]
    const float* __restrict__ r2,       // [256,256]
    const float* __restrict__ rb2,      // [256]
    const float* __restrict__ r3,       // [256,10]
    const float* __restrict__ rb3,      // [10]
    float* __restrict__ out)            // [B, C]
{
    const int b0  = blockIdx.x * K3_ROWS;
    const int tid = threadIdx.x;        // 0..1023
    const int k   = tid & (WF - 1);     // feature 0..255
    const int g   = tid >> 8;           // reduction group 0..3

    __shared__ float tp[K3_ROWS * TQ];  // 896 floats
    __shared__ float z1[K3_ROWS][WF];
    __shared__ float z2[K3_ROWS][WF];
    __shared__ float part[4][K3_ROWS][WF];
    __shared__ float red[8][CC];

    // ---- stage the 2 topo rows (coalesced) --------------------------------
    if (tid < K3_ROWS * TQ) tp[tid] = pooled[(size_t)b0 * TQ + tid];
    __syncthreads();

    // ---- layer 1: 448-deep, split 4x112, 8-wide double-buffered -----------
    {
        float acc0 = 0.0f, acc1 = 0.0f;
        const float* r1c = r1 + k;
        const int ibase = g * (TQ / 4);              // 112 per group
        float rv0[8], rv1[8];
#pragma unroll
        for (int e = 0; e < 8; ++e) rv0[e] = r1c[(ibase + e) * WF];
#pragma unroll 1
        for (int i0 = ibase; i0 < ibase + TQ / 4; i0 += 16) {
#pragma unroll
            for (int e = 0; e < 8; ++e) rv1[e] = r1c[(i0 + 8 + e) * WF];
#pragma unroll
            for (int e = 0; e < 8; ++e) {
                acc0 = fmaf(tp[i0 + e],      rv0[e], acc0);
                acc1 = fmaf(tp[TQ + i0 + e], rv0[e], acc1);
            }
            if (i0 + 16 < ibase + TQ / 4) {
#pragma unroll
                for (int e = 0; e < 8; ++e) rv0[e] = r1c[(i0 + 16 + e) * WF];
            }
#pragma unroll
            for (int e = 0; e < 8; ++e) {
                acc0 = fmaf(tp[i0 + 8 + e],      rv1[e], acc0);
                acc1 = fmaf(tp[TQ + i0 + 8 + e], rv1[e], acc1);
            }
        }
        part[g][0][k] = acc0;
        part[g][1][k] = acc1;
    }
    __syncthreads();
    if (tid < 2 * WF) {
        const int r = tid >> 8;         // row 0/1
        const int kk = tid & (WF - 1);
        z1[r][kk] = fmaxf(part[0][r][kk] + part[1][r][kk] +
                          part[2][r][kk] + part[3][r][kk] + rb1[kk], 0.0f);
    }
    __syncthreads();

    // ---- layer 2: 256-deep, split 4x64 ------------------------------------
    {
        float acc0 = 0.0f, acc1 = 0.0f;
        const float* r2c = r2 + k;
        const int ibase = g * (WF / 4);              // 64 per group
        float rv0[8], rv1[8];
#pragma unroll
        for (int e = 0; e < 8; ++e) rv0[e] = r2c[(ibase + e) * WF];
#pragma unroll 1
        for (int i0 = ibase; i0 < ibase + WF / 4; i0 += 16) {
#pragma unroll
            for (int e = 0; e < 8; ++e) rv1[e] = r2c[(i0 + 8 + e) * WF];
#pragma unroll
            for (int e = 0; e < 8; ++e) {
                acc0 = fmaf(z1[0][i0 + e], rv0[e], acc0);
                acc1 = fmaf(z1[1][i0 + e], rv0[e], acc1);
            }
            if (i0 + 16 < ibase + WF / 4) {
#pragma unroll
                for (int e = 0; e < 8; ++e) rv0[e] = r2c[(i0 + 16 + e) * WF];
            }
#pragma unroll
            for (int e = 0; e < 8; ++e) {
                acc0 = fmaf(z1[0][i0 + 8 + e], rv1[e], acc0);
                acc1 = fmaf(z1[1][i0 + 8 + e], rv1[e], acc1);
            }
        }
        part[g][0][k] = acc0;
        part[g][1][k] = acc1;
    }
    __syncthreads();
    if (tid < 2 * WF) {
        const int r = tid >> 8;
        const int kk = tid & (WF - 1);
        z2[r][kk] = fmaxf(part[0][r][kk] + part[1][r][kk] +
                          part[2][r][kk] + part[3][r][kk] + rb2[kk], 0.0f);
    }
    __syncthreads();

    // ---- layer 3: outer product + wave reduce (threads 0..511) ------------
    if (tid < 512) {
        const int r    = tid >> 8;      // row 0/1
        const int kk   = tid & (WF - 1);
        const int lane = tid & 63;
        const int wvi  = tid >> 6;      // 0..7
        const float z = z2[r][kk];
        float p[CC];
#pragma unroll
        for (int c = 0; c < CC; ++c) p[c] = z * r3[kk * CC + c];
#pragma unroll
        for (int off = 32; off >= 1; off >>= 1) {
#pragma unroll
            for (int c = 0; c < CC; ++c) p[c] += __shfl_xor(p[c], off, 64);
        }
        if (lane == 0) {
#pragma unroll
            for (int c = 0; c < CC; ++c) red[wvi][c] = p[c];
        }
    }
    __syncthreads();
    if (tid < K3_ROWS * CC) {
        const int r = tid / CC;
        const int c = tid % CC;
        out[(size_t)(b0 + r) * CC + c] =
            red[r * 4 + 0][c] + red[r * 4 + 1][c] +
            red[r * 4 + 2][c] + red[r * 4 + 3][c] + rb3[c];
    }
}

// ---------------------------------------------------------------------------
extern "C" void kernel_launch(void* const* d_in, const int* in_sizes, int n_in,
                              void* d_out, int out_size, void* d_ws, size_t ws_size,
                              hipStream_t stream)
{
    const float* diagms = (const float*)d_in[0];
    // d_in[1] = seg_ids (int32) — structurally n/P with equal counts; unused.
    const float* theta  = (const float*)d_in[2];
    const float* w1     = (const float*)d_in[3];
    const float* b1     = (const float*)d_in[4];
    const float* w2     = (const float*)d_in[5];
    const float* b2     = (const float*)d_in[6];
    const float* w3     = (const float*)d_in[7];
    const float* b3     = (const float*)d_in[8];
    const float* r1     = (const float*)d_in[9];
    const float* rb1    = (const float*)d_in[10];
    const float* r2     = (const float*)d_in[11];
    const float* rb2    = (const float*)d_in[12];
    const float* r3     = (const float*)d_in[13];
    const float* rb3    = (const float*)d_in[14];
    float* out = (float*)d_out;

    float* w_buf  = (float*)d_ws;            // [T*N]
    float* pooled = w_buf + (size_t)TT * NN; // [B, T*Q]

    const int total = TT * NN;               // 716800

    // K1 v2: per-point weight MLP (MFMA, lgkm-hygiene + DPP epilogue)
    point_weight_kernel<<<total / 256, 256, 0, stream>>>(
        diagms, w1, b1, w2, b2, w3, b3, w_buf);

    // K2: gaussian rep + segment mean-pool (float4-packed LDS)
    rep_pool_kernel<<<TT * BB, 256, 0, stream>>>(diagms, theta, w_buf, pooled);

    // K3: final rho MLP (TLP-pipelined v3)
    rho_kernel<<<BB / K3_ROWS, 1024, 0, stream>>>(
        pooled, r1, rb1, r2, rb2, r3, rb3, out);
}